// Round 5
// baseline (864.743 us; speedup 1.0000x reference)
//
#include <hip/hip_runtime.h>
#include <hip/hip_bf16.h>
#include <math.h>
#include <stdio.h>

// BiMambaBlock: bidirectional Mamba forward.
// B=4, L=2048, D_MODEL=1024, D_INNER=2048, D_STATE=16, D_CONV=4, DT_RANK=64.
// Inputs/output fp32; GEMMs run bf16 MFMA (fp32 acc) via cast kernels.
//
// R11 -> R12: k_gemm256 strict ping-pong schedule, ONE barrier per K-tile
// (was 4). KTILE(CB) reads buf CB only, stages tile kt+1 into CB^1 only:
//  - no intra-K-tile stage/read hazard -> all 24 ds_reads issue up-front;
//    MFMA clusters gate on counted lgkmcnt(12/8/0)+sched_barrier(0)
//    (rule #18: hipcc hoists reg-only MFMA past inline-asm waits).
//  - vmcnt(8) at KTILE start (after issuing own 8 stages) = prev tile
//    landed; tail KTILE uses vmcnt(0). Closing barrier = stage safety.
//  - waves de-phase within the K-tile -> LDS pipe overlaps MFMA pipe.
//  - af0/af1 held separately (+32 VGPR, ~190 total, still 2 waves/SIMD).
// MFMA accumulation order bit-identical -> absmax unchanged (race detector).
// All other kernels unchanged from R11.

using u16 = unsigned short;
using u32 = unsigned int;

typedef __bf16 bf16x8 __attribute__((ext_vector_type(8)));
typedef float  f32x4  __attribute__((ext_vector_type(4)));
typedef u32    u32x4  __attribute__((ext_vector_type(4)));
typedef u16    u16x4  __attribute__((ext_vector_type(4)));

#define DEVINL __device__ __forceinline__

DEVINL float b2f(u16 u) { union { u32 i; float f; } v; v.i = ((u32)u) << 16; return v.f; }
DEVINL u16 f2b(float f) {
  union { float f; u32 i; } v; v.f = f;
  u32 i = v.i;
  return (u16)((i + 0x7FFFu + ((i >> 16) & 1u)) >> 16);  // RNE; inputs are tame (no NaN)
}

#define L2E 1.4426950408889634f
#define LN2 0.6931471805599453f

// silu(a) = a/(1+e^-a) via HW exp2/rcp (1-ulp each; << bf16 quantization)
DEVINL float fast_silu(float a) {
  const float e = __builtin_amdgcn_exp2f(-a * L2E);
  return a * __builtin_amdgcn_rcpf(1.f + e);
}
// softplus(x) = ln(1+e^x) via HW exp2/log2; guard keeps large-x exact
DEVINL float fast_softplus(float x) {
  if (x > 20.f) return x;
  return LN2 * __builtin_amdgcn_logf(1.f + __builtin_amdgcn_exp2f(x * L2E));
}

DEVINL void gl_lds16(const u16* g, u16* l) {
  __builtin_amdgcn_global_load_lds(
      (__attribute__((address_space(1))) void*)const_cast<u16*>(g),
      (__attribute__((address_space(3))) void*)l, 16, 0, 0);
}

// ---------------------------------------------------------------------------
// 256x256 ping-pong GEMM (in_proj): C[m,n] = sum_k A[m,k]*B[n,k], bf16->f32.
// 512 threads = 8 waves; wave w owns rows (w>>2)*64, cols (w&3)*32 of each
// 128x128 C-quadrant. K-tile BK=64; buffers strictly alternate (ping-pong).
// LDS: A [0,64K) B [64K,128K), each: [buf][half(128rows)][row][64 bf16],
// swizzled colbyte ^= ((row&7)<<4).
// ---------------------------------------------------------------------------
#define BAR()    asm volatile("s_barrier" ::: "memory")
#define LGKM(N)  asm volatile("s_waitcnt lgkmcnt(" #N ")" ::: "memory")
#define VM8()    asm volatile("s_waitcnt vmcnt(8)" ::: "memory")
#define VM0()    asm volatile("s_waitcnt vmcnt(0)" ::: "memory")
#define SCHB()   __builtin_amdgcn_sched_barrier(0)
#define NOPS     ((void)0)

__global__ __launch_bounds__(512, 2) void k_gemm256(
    const u16* __restrict__ A, int lda, int flipA,
    const u16* __restrict__ Bw, int ldb,
    u16* __restrict__ C, int ldc, int K)
{
  extern __shared__ __align__(16) char lds[];  // 131072 B

  const int tid  = threadIdx.x;
  const int lane = tid & 63;
  const int wid  = tid >> 6;

  const int mBase = blockIdx.x * 256;
  const int nBase = blockIdx.y * 256;

  // ---- staging: granule G = wid*128 + i*64 + lane (16 B each), row = G>>3,
  // slot = G&7; source col pre-swizzled so linear LDS + swizzled read match.
  const int rloc = lane >> 3;                       // 0..7
  const int scol = ((lane & 7) ^ rloc) << 3;        // elems (8 per granule)
  const u16* srcA[2][2];
  const u16* srcB[2][2];
#pragma unroll
  for (int h = 0; h < 2; ++h)
#pragma unroll
    for (int i = 0; i < 2; ++i) {
      int ra = mBase + h * 128 + wid * 16 + i * 8 + rloc;
      if (flipA) ra ^= 2047;                        // batch-local time flip
      const int rb = nBase + h * 128 + wid * 16 + i * 8 + rloc;
      srcA[h][i] = A  + (long long)ra * lda + scol;
      srcB[h][i] = Bw + (long long)rb * ldb + scol;
    }
  u16* const dA = (u16*)lds + wid * 1024;           // A region base, elems
  u16* const dB = (u16*)lds + 32768 + wid * 1024;   // B region base, elems

  // ---- ds_read byte offsets (within lds); swz makes every 16-lane group
  // cover all 8 16B-slots of a 128B row -> 2-way bank aliasing (free).
  const int lhi16 = (lane >> 4) * 16;
  const int swz   = (lane & 7) << 4;
  const int rdA   = ((wid >> 2) * 64 + (lane & 15)) * 128 + (lhi16 ^ swz);
  const int rdAx  = rdA ^ 64;                       // kk=1 (+32 elems)
  const int rdB   = 65536 + ((wid & 3) * 32 + (lane & 15)) * 128 + (lhi16 ^ swz);
  const int rdBx  = rdB ^ 64;

  f32x4 acc[2][2][4][2];
#pragma unroll
  for (int a = 0; a < 2; ++a)
#pragma unroll
    for (int b = 0; b < 2; ++b)
#pragma unroll
      for (int c = 0; c < 4; ++c)
#pragma unroll
        for (int d = 0; d < 2; ++d) acc[a][b][c][d] = (f32x4){0.f, 0.f, 0.f, 0.f};

  bf16x8 af0[4][2], af1[4][2], bq0[2][2], bq1[2][2];

#define LDSV(off) (*(const bf16x8*)(lds + (off)))
#define READ_A(CB, QM, DST) do {                                               \
  _Pragma("unroll") for (int fm = 0; fm < 4; ++fm) {                           \
    DST[fm][0] = LDSV((CB)*32768 + (QM)*16384 + fm*2048 + rdA);                \
    DST[fm][1] = LDSV((CB)*32768 + (QM)*16384 + fm*2048 + rdAx); }             \
} while (0)
#define READ_B(CB, QN, DST) do {                                               \
  _Pragma("unroll") for (int fn = 0; fn < 2; ++fn) {                           \
    DST[fn][0] = LDSV((CB)*32768 + (QN)*16384 + fn*2048 + rdB);                \
    DST[fn][1] = LDSV((CB)*32768 + (QN)*16384 + fn*2048 + rdBx); }             \
} while (0)
#define MMA(QM, QN, AF, BFR) do {                                              \
  __builtin_amdgcn_s_setprio(1);                                              \
  _Pragma("unroll") for (int fm = 0; fm < 4; ++fm)                             \
  _Pragma("unroll") for (int fn = 0; fn < 2; ++fn)                             \
  _Pragma("unroll") for (int kk = 0; kk < 2; ++kk)                             \
    acc[QM][QN][fm][fn] = __builtin_amdgcn_mfma_f32_16x16x32_bf16(             \
        AF[fm][kk], BFR[fn][kk], acc[QM][QN][fm][fn], 0, 0, 0);                \
  __builtin_amdgcn_s_setprio(0);                                              \
} while (0)
// stage all 8 half-tiles of tile KT into buffer CB (A half0/1, B half0/1)
#define STAGE_ALL(CB, KT) do {                                                 \
  gl_lds16(srcA[0][0] + (KT)*64, dA + (CB)*16384);                             \
  gl_lds16(srcA[0][1] + (KT)*64, dA + (CB)*16384 + 512);                       \
  gl_lds16(srcA[1][0] + (KT)*64, dA + (CB)*16384 + 8192);                      \
  gl_lds16(srcA[1][1] + (KT)*64, dA + (CB)*16384 + 8192 + 512);                \
  gl_lds16(srcB[0][0] + (KT)*64, dB + (CB)*16384);                             \
  gl_lds16(srcB[0][1] + (KT)*64, dB + (CB)*16384 + 512);                       \
  gl_lds16(srcB[1][0] + (KT)*64, dB + (CB)*16384 + 8192);                      \
  gl_lds16(srcB[1][1] + (KT)*64, dB + (CB)*16384 + 8192 + 512);                \
} while (0)

// one K-tile: stage next tile into CB^1, wait prev stages (vmcnt), issue all
// 24 ds_reads of CB, MFMA clusters gated by counted lgkm. ONE closing barrier
// (stage safety: next KTILE overwrites CB only after all waves read it).
#define KTILE2(CB, STG, VMW) do {                                              \
  STG;                                                                         \
  VMW;                                                                         \
  READ_A(CB, 0, af0); READ_B(CB, 0, bq0); READ_B(CB, 1, bq1);                  \
  READ_A(CB, 1, af1);                                                          \
  LGKM(12); SCHB();                                                            \
  MMA(0, 0, af0, bq0);                                                         \
  LGKM(8); SCHB();                                                             \
  MMA(0, 1, af0, bq1);                                                         \
  LGKM(0); SCHB();                                                             \
  MMA(1, 1, af1, bq1);                                                         \
  MMA(1, 0, af1, bq0);                                                         \
  BAR();                                                                       \
} while (0)

  // prologue: tile 0 -> buf0 (8 loads in flight; invariant: 8 outstanding
  // at each KTILE entry, targeting the buffer that KTILE reads).
  STAGE_ALL(0, 0);

  // K = 1024 -> 16 K-tiles; 14 in the steady loop + 2 peeled tail tiles.
  for (int it = 0; it < 7; ++it) {
    const int kt = 2 * it;
    KTILE2(0, STAGE_ALL(1, kt + 1), VM8());
    KTILE2(1, STAGE_ALL(0, kt + 2), VM8());
  }
  KTILE2(0, STAGE_ALL(1, 15), VM8());
  KTILE2(1, NOPS, VM0());

  // epilogue: D mapping col = lane&15, row = (lane>>4)*4 + reg  [m89]
  const int rq = (lane >> 4) << 2;
  const int cn = lane & 15;
  const long long mW = mBase + (wid >> 2) * 64;
  const int nW = nBase + (wid & 3) * 32;
#pragma unroll
  for (int qm = 0; qm < 2; ++qm)
#pragma unroll
    for (int qn = 0; qn < 2; ++qn)
#pragma unroll
      for (int fm = 0; fm < 4; ++fm)
#pragma unroll
        for (int fn = 0; fn < 2; ++fn)
#pragma unroll
          for (int r = 0; r < 4; ++r) {
            const long long m = mW + qm * 128 + fm * 16 + rq + r;
            const int n = nW + qn * 128 + fn * 16 + cn;
            C[m * ldc + n] = f2b(acc[qm][qn][fm][fn][r]);
          }
#undef LDSV
#undef READ_A
#undef READ_B
#undef MMA
#undef STAGE_ALL
#undef KTILE2
}

// ---------------------------------------------------------------------------
// GEMM: C[m,n] = sum_k A[m,k] * B[n,k]   (both K-major, bf16 in, fp32 acc)
// 128x128 tile, BK=64, 256 threads (4 waves, each 64x64 = 4x4 mfma 16x16x32).
// MODE 1: softplus(acc + f1[n]) -> bf16
// MODE 2: store fp32              MODE 3: fp32 store to out2 at m^2047, += f2
// MODE 4: n<64 -> bf16 Cout; n in [64,96) -> split fp32 to f1(B)/f2(C)
// ---------------------------------------------------------------------------
template <int MODE>
__global__ __launch_bounds__(256) void k_gemm(
    const u16* __restrict__ A, int lda, int flipA,
    const u16* __restrict__ Bw, int ldb,
    void* __restrict__ Cout, int ldc, int K,
    float* __restrict__ f1, float* __restrict__ f2,
    float* __restrict__ out2)
{
  __shared__ __align__(16) u16 As[128 * 64];
  __shared__ __align__(16) u16 Bs[128 * 64];

  const int tid  = threadIdx.x;
  const int lane = tid & 63;
  const int wid  = tid >> 6;

  const int mBase = blockIdx.x * 128;
  const int nBase = blockIdx.y * 128;

  f32x4 acc[4][4];
#pragma unroll
  for (int i = 0; i < 4; ++i)
#pragma unroll
    for (int j = 0; j < 4; ++j) acc[i][j] = (f32x4){0.f, 0.f, 0.f, 0.f};

  const int wm = (wid & 1) * 64;
  const int wn = (wid >> 1) * 64;
  const int lrow = lane & 15;
  const int lk   = (lane >> 4) * 8;
  const int sr = tid >> 3;         // staging row within 32-row group [0,32)
  const int sc = (tid & 7) * 8;    // staging col (8 bf16 = 16 B)

  for (int k0 = 0; k0 < K; k0 += 64) {
#pragma unroll
    for (int i = 0; i < 4; ++i) {
      int ra = mBase + i * 32 + sr;
      if (flipA) ra ^= 2047;               // SGPR-uniform time flip
      const int rb = nBase + i * 32 + sr;
      u16* la = &As[(i * 256 + wid * 64) * 8];
      u16* lb = &Bs[(i * 256 + wid * 64) * 8];
      gl_lds16(A  + (long long)ra * lda + (k0 + sc), la);
      gl_lds16(Bw + (long long)rb * ldb + (k0 + sc), lb);
    }
    __syncthreads();
#pragma unroll
    for (int kk = 0; kk < 64; kk += 32) {
      bf16x8 af[4], bfr[4];
#pragma unroll
      for (int f = 0; f < 4; ++f) {
        af[f]  = *(const bf16x8*)&As[(wm + f * 16 + lrow) * 64 + kk + lk];
        bfr[f] = *(const bf16x8*)&Bs[(wn + f * 16 + lrow) * 64 + kk + lk];
      }
#pragma unroll
      for (int fm = 0; fm < 4; ++fm)
#pragma unroll
        for (int fn = 0; fn < 4; ++fn)
          acc[fm][fn] = __builtin_amdgcn_mfma_f32_16x16x32_bf16(af[fm], bfr[fn], acc[fm][fn], 0, 0, 0);
    }
    __syncthreads();
  }

  const int rowq = (lane >> 4) * 4;
  const int coln = lane & 15;
#pragma unroll
  for (int fm = 0; fm < 4; ++fm) {
#pragma unroll
    for (int fn = 0; fn < 4; ++fn) {
#pragma unroll
      for (int r = 0; r < 4; ++r) {
        const long long m = mBase + wm + fm * 16 + rowq + r;
        const long long n = nBase + wn + fn * 16 + coln;
        const float v = acc[fm][fn][r];
        if constexpr (MODE == 0) {
          ((u16*)Cout)[m * ldc + n] = f2b(v);
        } else if constexpr (MODE == 1) {
          ((u16*)Cout)[m * ldc + n] = f2b(fast_softplus(v + f1[(int)n]));
        } else if constexpr (MODE == 2) {
          ((float*)Cout)[m * ldc + n] = v;
        } else if constexpr (MODE == 3) {
          const long long mf = m ^ 2047;  // time flip within batch (L=2048)
          out2[mf * ldc + n] = v + f2[mf * ldc + n];
        } else {  // MODE 4 (x_proj): dt-raw -> proj bf16; B/C -> fp32 split
          if (n < 64)       ((u16*)Cout)[m * ldc + n] = f2b(v);
          else if (n < 80)  f1[m * 16 + (n - 64)] = v;
          else if (n < 96)  f2[m * 16 + (n - 80)] = v;
        }
      }
    }
  }
}

// ---------------------------------------------------------------------------
// fused per-dir prep: [0,4096) castw inw | [4096,5120) pad+cast xw |
// [5120,5248) castw dtw | [5248,5376) A2 | [5376,5408) cwT transpose
// ---------------------------------------------------------------------------
__global__ __launch_bounds__(256) void k_prep(
    const float* __restrict__ inw_d, u16* __restrict__ inwB,
    const float* __restrict__ xpw_d, u16* __restrict__ xw_pad,
    const float* __restrict__ dtw_d, u16* __restrict__ dtwB,
    const float* __restrict__ alog_d, float* __restrict__ A2,
    const float* __restrict__ cw_d, float* __restrict__ cwT)
{
  const int bx = blockIdx.x;
  const int tid = threadIdx.x;
  if (bx < 4096) {
    const int i = bx * 256 + tid;
    const f32x4 v = ((const f32x4*)inw_d)[i];
    u16x4 o = {f2b(v[0]), f2b(v[1]), f2b(v[2]), f2b(v[3])};
    ((u16x4*)inwB)[i] = o;
  } else if (bx < 5120) {
    const int idx = (bx - 4096) * 256 + tid;  // [0, 128*2048)
    const int c = idx & 2047, r = idx >> 11;
    xw_pad[idx] = (r < 96) ? f2b(xpw_d[r * 2048 + c]) : (u16)0;
  } else if (bx < 5248) {
    const int i = (bx - 5120) * 256 + tid;    // 2048*64/4
    const f32x4 v = ((const f32x4*)dtw_d)[i];
    u16x4 o = {f2b(v[0]), f2b(v[1]), f2b(v[2]), f2b(v[3])};
    ((u16x4*)dtwB)[i] = o;
  } else if (bx < 5376) {
    const int idx = (bx - 5248) * 256 + tid;  // [0, 2048*16)
    A2[idx] = -expf(alog_d[idx]) * L2E;  // A * log2(e)
  } else {
    const int idx = (bx - 5376) * 256 + tid;  // [0, 8192)
    const int d = idx & 2047, k = idx >> 11;
    cwT[k * 2048 + d] = cw_d[d * 4 + k];      // [2048][4] -> [4][2048]
  }
}

__global__ __launch_bounds__(256) void k_castw(const float* __restrict__ src,
                                               u16* __restrict__ dst) {
  const int i = blockIdx.x * 256 + threadIdx.x;
  const f32x4 v = ((const f32x4*)src)[i];
  u16x4 o = {f2b(v[0]), f2b(v[1]), f2b(v[2]), f2b(v[3])};
  ((u16x4*)dst)[i] = o;
}

// x fp32 [4][2048][1024] -> bf16 (no flip; dir1 flip happens in GEMM staging)
__global__ __launch_bounds__(256) void k_cast_x(const float* __restrict__ x,
                                                u16* __restrict__ xA) {
  const int idx = blockIdx.x * 256 + threadIdx.x;  // [0, 4*2048*256)
  const f32x4 v = ((const f32x4*)x)[idx];
  u16x4 o = {f2b(v[0]), f2b(v[1]), f2b(v[2]), f2b(v[3])};
  ((u16x4*)xA)[idx] = o;
}

// ---------------------------------------------------------------------------
// depthwise causal conv (k=4) + bias + silu.  xi lives in xz cols [0,2048).
// ---------------------------------------------------------------------------
__global__ __launch_bounds__(256) void k_conv(const u16* __restrict__ xz,
                                              const float* __restrict__ cwT,
                                              const float* __restrict__ cb,
                                              u16* __restrict__ xc) {
  const int idx = blockIdx.x * 256 + threadIdx.x;  // [0, 8192*256)
  const int d8  = idx & 255;
  const int gr  = idx >> 8;
  const int t   = gr & 2047;
  const int d0  = d8 * 8;

  float acc[8];
  {
    const f32x4 b0 = *(const f32x4*)(cb + d0);
    const f32x4 b1 = *(const f32x4*)(cb + d0 + 4);
#pragma unroll
    for (int j = 0; j < 4; ++j) { acc[j] = b0[j]; acc[4 + j] = b1[j]; }
  }

#pragma unroll
  for (int k = 0; k < 4; ++k) {
    const int tt = t - 3 + k;
    if (tt < 0) continue;
    const u32x4 v = *(const u32x4*)(xz + (long long)(gr + k - 3) * 4096 + d0);
    const u16* pv = (const u16*)&v;
    const f32x4 w0 = *(const f32x4*)(cwT + k * 2048 + d0);
    const f32x4 w1 = *(const f32x4*)(cwT + k * 2048 + d0 + 4);
#pragma unroll
    for (int j = 0; j < 4; ++j) {
      acc[j]     = fmaf(w0[j], b2f(pv[j]), acc[j]);
      acc[4 + j] = fmaf(w1[j], b2f(pv[4 + j]), acc[4 + j]);
    }
  }
  u16 o[8];
#pragma unroll
  for (int j = 0; j < 8; ++j) {
    o[j] = f2b(fast_silu(acc[j]));
  }
  *(u32x4*)(xc + (long long)gr * 2048 + d0) = *(const u32x4*)o;
}

// ---------------------------------------------------------------------------
// scan phase A: per-chunk local scan (h from 0), CHUNK=64. Writes ONLY chunk
// summaries hbuf[b][c][s][d] (local end-state) and sumdt[b][c][d].
// grid: 4(b) * 32(chunk) * 8(dchunk) = 1024 blocks
// ---------------------------------------------------------------------------
__global__ __launch_bounds__(256) void k_scanA(
    const u16* __restrict__ dt, const u16* __restrict__ xc,
    const float* __restrict__ Bf, const float* __restrict__ A2,
    float* __restrict__ hbuf, float* __restrict__ sumdt)
{
  const int tid = threadIdx.x;
  const int bx  = blockIdx.x;
  const int d     = (bx & 7) * 256 + tid;
  const int chunk = (bx >> 3) & 31;
  const int b     = bx >> 8;

  float a2[16];
#pragma unroll
  for (int s = 0; s < 16; ++s) a2[s] = A2[d * 16 + s];

  float h[16];
#pragma unroll
  for (int s = 0; s < 16; ++s) h[s] = 0.f;
  float sdt = 0.f;

  const long long rowBase = (long long)b * 2048 + chunk * 64;
  for (int t0 = 0; t0 < 64; ++t0) {
    const long long gr = rowBase + t0;
    const float dtv = b2f(dt[gr * 2048 + d]);
    const float xcv = b2f(xc[gr * 2048 + d]);
    sdt += dtv;
    const float dtx = dtv * xcv;
    float Bv[16];
    *(f32x4*)&Bv[0]  = *(const f32x4*)(Bf + gr * 16);
    *(f32x4*)&Bv[4]  = *(const f32x4*)(Bf + gr * 16 + 4);
    *(f32x4*)&Bv[8]  = *(const f32x4*)(Bf + gr * 16 + 8);
    *(f32x4*)&Bv[12] = *(const f32x4*)(Bf + gr * 16 + 12);
#pragma unroll
    for (int s = 0; s < 16; ++s) {
      const float dA = __builtin_amdgcn_exp2f(a2[s] * dtv);
      h[s] = fmaf(h[s], dA, dtx * Bv[s]);
    }
  }
  const long long cbi = (long long)b * 32 + chunk;
#pragma unroll
  for (int s = 0; s < 16; ++s) hbuf[(cbi * 16 + s) * 2048 + d] = h[s];
  sumdt[cbi * 2048 + d] = sdt;
}

// phase B: chain chunk states IN PLACE: hbuf[c] goes local-end-state ->
// entering-state. s-chains are independent -> split x2 (8 s per block).
// grid: 4(b) * 8(dchunk) * 2(sgroup) = 64 blocks
__global__ __launch_bounds__(256) void k_scanB(
    const float* __restrict__ A2, float* __restrict__ hbuf,
    const float* __restrict__ sumdt)
{
  const int tid = threadIdx.x;
  const int bx  = blockIdx.x;
  const int d   = (bx & 7) * 256 + tid;
  const int sg  = ((bx >> 3) & 1) * 8;
  const int b   = bx >> 4;

  float a2[8];
#pragma unroll
  for (int s = 0; s < 8; ++s) a2[s] = A2[d * 16 + sg + s];
  float h[8];
#pragma unroll
  for (int s = 0; s < 8; ++s) h[s] = 0.f;

  const long long base = (long long)b * 32;
  for (int c = 0; c < 32; ++c) {
    const long long cbi = base + c;
    const float sd = sumdt[cbi * 2048 + d];
#pragma unroll
    for (int s = 0; s < 8; ++s) {
      float* p = &hbuf[(cbi * 16 + sg + s) * 2048 + d];
      const float loc = *p;      // local end-state of chunk c
      *p = h[s];                 // replace with state ENTERING chunk c
      const float P = __builtin_amdgcn_exp2f(a2[s] * sd);
      h[s] = fmaf(h[s], P, loc);
    }
  }
}

// ---------------------------------------------------------------------------
// phase C: true recurrence from entering state + gate, y written once.
// y = h.C with h = h*dA + dtx*B stepped from hbuf state; then
// y_fin = (y + xc*Dp) * silu(z). grid 1024 (same decomposition as A).
// ---------------------------------------------------------------------------
__global__ __launch_bounds__(256) void k_scanC(
    const u16* __restrict__ dt, const u16* __restrict__ xc,
    const float* __restrict__ Bf, const float* __restrict__ Cf,
    const float* __restrict__ A2, const float* __restrict__ hbuf,
    const float* __restrict__ Dp, u16* __restrict__ yz)
{
  const int tid = threadIdx.x;
  const int bx  = blockIdx.x;
  const int d     = (bx & 7) * 256 + tid;
  const int chunk = (bx >> 3) & 31;
  const int b     = bx >> 8;
  const float dp  = Dp[d];

  float a2[16];
#pragma unroll
  for (int s = 0; s < 16; ++s) a2[s] = A2[d * 16 + s];

  const long long cbi = (long long)b * 32 + chunk;
  float h[16];
#pragma unroll
  for (int s = 0; s < 16; ++s) h[s] = hbuf[(cbi * 16 + s) * 2048 + d];

  const long long rowBase = (long long)b * 2048 + chunk * 64;
  for (int t0 = 0; t0 < 64; ++t0) {
    const long long gr = rowBase + t0;
    const float dtv = b2f(dt[gr * 2048 + d]);
    const float xcv = b2f(xc[gr * 2048 + d]);
    const float dtx = dtv * xcv;
    float Bv[16], Cv[16];
    *(f32x4*)&Bv[0]  = *(const f32x4*)(Bf + gr * 16);
    *(f32x4*)&Bv[4]  = *(const f32x4*)(Bf + gr * 16 + 4);
    *(f32x4*)&Bv[8]  = *(const f32x4*)(Bf + gr * 16 + 8);
    *(f32x4*)&Bv[12] = *(const f32x4*)(Bf + gr * 16 + 12);
    *(f32x4*)&Cv[0]  = *(const f32x4*)(Cf + gr * 16);
    *(f32x4*)&Cv[4]  = *(const f32x4*)(Cf + gr * 16 + 4);
    *(f32x4*)&Cv[8]  = *(const f32x4*)(Cf + gr * 16 + 8);
    *(f32x4*)&Cv[12] = *(const f32x4*)(Cf + gr * 16 + 12);
    float y = 0.f;
#pragma unroll
    for (int s = 0; s < 16; ++s) {
      const float dA = __builtin_amdgcn_exp2f(a2[s] * dtv);
      h[s] = fmaf(h[s], dA, dtx * Bv[s]);
      y = fmaf(h[s], Cv[s], y);
    }
    const float z = b2f(yz[gr * 4096 + 2048 + d]);
    const float yv = (y + xcv * dp) * fast_silu(z);
    yz[gr * 4096 + d] = f2b(yv);
  }
}

// ---------------------------------------------------------------------------
extern "C" void kernel_launch(void* const* d_in, const int* in_sizes, int n_in,
                              void* d_out, int out_size, void* d_ws, size_t ws_size,
                              hipStream_t stream) {
  const float* x    = (const float*)d_in[0];
  const float* inw  = (const float*)d_in[1];
  const float* cw   = (const float*)d_in[2];
  const float* cb   = (const float*)d_in[3];
  const float* xpw  = (const float*)d_in[4];
  const float* dtw  = (const float*)d_in[5];
  const float* dtb  = (const float*)d_in[6];
  const float* alog = (const float*)d_in[7];
  const float* Dp   = (const float*)d_in[8];
  const float* ow   = (const float*)d_in[9];
  float* out = (float*)d_out;

  // workspace layout (bytes) — per-direction buffers reused across dir 0/1.
  char* ws = (char*)d_ws;
  float* outacc = (float*)(ws + 0);          //  33,554,432  [8192][1024] fp32
  u16*   xz_d   = (u16*)(ws + 33554432);     //  67,108,864  [8192][4096] xi|z -> y|z
  u16*   xc_d   = (u16*)(ws + 100663296);    //  33,554,432  [8192][2048]
  u16*   inwB   = (u16*)(ws + 100663296);    //   8,388,608  (xc dead during in_proj)
  u16*   dt_d   = (u16*)(ws + 134217728);    //  33,554,432  [8192][2048]
  u16*   owB    = (u16*)(ws + 134217728);    //   4,194,304  (dt dead after scanC)
  u16*   xA     = (u16*)(ws + 167772160);    //  16,777,216  [8192][1024] persistent
  u16*   proj_d = (u16*)(ws + 184549376);    //   1,048,576  [8192][64] (stride 64)
  u16*   xw_pad = (u16*)(ws + 185597952);    //     524,288  [128][2048]
  float* A2     = (float*)(ws + 186122240);  //     131,072  [2048][16]
  float* Bf     = (float*)(ws + 186253312);  //     524,288  [8192][16]
  float* Cf     = (float*)(ws + 186777600);  //     524,288
  float* hbuf   = (float*)(ws + 187301888);  //  16,777,216  [4][32][16][2048] in-place
  float* sumdt  = (float*)(ws + 204079104);  //   1,048,576  [4][32][2048]
  u16*   dtwB   = (u16*)(ws + 205127680);    //     262,144  [2048][64]
  float* cwT    = (float*)(ws + 205389824);  //      32,768  [4][2048]
  const size_t NEED = 205422592;  // <= 205,651,968 proven available (R2 ran)

  (void)in_sizes; (void)n_in; (void)out_size;
  if (ws_size < NEED) {  // deterministic guard: leaves d_out zeroed -> clean fail
    fprintf(stderr, "[BiMamba] ws_size=%zu < needed %zu — aborting launch\n", ws_size, NEED);
    return;
  }

  // allow 128 KiB dynamic LDS for the ping-pong GEMM (host-side, capture-safe)
  static bool attr_set = false;
  if (!attr_set) {
    (void)hipFuncSetAttribute((const void*)k_gemm256,
                              hipFuncAttributeMaxDynamicSharedMemorySize, 131072);
    attr_set = true;
  }

  k_cast_x<<<8192, 256, 0, stream>>>(x, xA);  // once; dir1 flips in staging

  for (int dir = 0; dir < 2; ++dir) {
    const float* inw_d = inw + (long long)dir * 4096 * 1024;
    const float* cw_d  = cw  + dir * 2048 * 4;
    const float* cb_d  = cb  + dir * 2048;
    const float* xpw_d = xpw + dir * 96 * 2048;
    const float* dtw_d = dtw + dir * 2048 * 64;
    const float* dtb_d = dtb + dir * 2048;
    const float* al_d  = alog + dir * 2048 * 16;
    const float* Dp_d  = Dp  + dir * 2048;
    const float* ow_d  = ow  + (long long)dir * 1024 * 2048;

    k_prep<<<5408, 256, 0, stream>>>(inw_d, inwB, xpw_d, xw_pad,
                                     dtw_d, dtwB, al_d, A2, cw_d, cwT);

    // in_proj: xz = xA[8192,1024] x inwB[4096,1024]^T  (dir1: A rows ^2047)
    // 256^2 ping-pong template, 512 thr, 128 KiB LDS
    k_gemm256<<<dim3(32, 16), 512, 131072, stream>>>(
        xA, 1024, dir, inwB, 1024, xz_d, 4096, 1024);

    k_conv<<<8192, 256, 0, stream>>>(xz_d, cwT, cb_d, xc_d);

    // x_proj: proj(dt-raw, stride 64) + Bf/Cf fp32 split, fused epilogue
    k_gemm<4><<<dim3(64, 1), 256, 0, stream>>>(
        xc_d, 2048, 0, xw_pad, 2048, proj_d, 64, 2048, Bf, Cf, nullptr);

    // dt_proj: dt = softplus(proj[8192,64] x dtwB[2048,64]^T + dtb)
    k_gemm<1><<<dim3(64, 16), 256, 0, stream>>>(
        proj_d, 64, 0, dtwB, 64, dt_d, 2048, 64,
        const_cast<float*>(dtb_d), nullptr, nullptr);

    k_scanA<<<1024, 256, 0, stream>>>(dt_d, xc_d, Bf, A2, hbuf, sumdt);
    k_scanB<<<64, 256, 0, stream>>>(A2, hbuf, sumdt);
    k_scanC<<<1024, 256, 0, stream>>>(dt_d, xc_d, Bf, Cf, A2, hbuf, Dp_d, xz_d);

    // out_proj weights -> bf16 (dt region dead after scanC)
    k_castw<<<2048, 256, 0, stream>>>(ow_d, owB);

    if (dir == 0) {
      k_gemm<2><<<dim3(64, 8), 256, 0, stream>>>(
          xz_d, 4096, 0, owB, 2048, outacc, 1024, 2048, nullptr, nullptr, nullptr);
    } else {
      k_gemm<3><<<dim3(64, 8), 256, 0, stream>>>(
          xz_d, 4096, 0, owB, 2048, nullptr, 1024, 2048,
          nullptr, outacc, out);
    }
  }
}

// Round 6
// 787.273 us; speedup vs baseline: 1.0984x; 1.0984x over previous
//
#include <hip/hip_runtime.h>
#include <hip/hip_bf16.h>
#include <math.h>
#include <stdio.h>

// BiMambaBlock: bidirectional Mamba forward.
// B=4, L=2048, D_MODEL=1024, D_INNER=2048, D_STATE=16, D_CONV=4, DT_RANK=64.
// Inputs/output fp32; GEMMs run bf16 MFMA (fp32 acc) via cast kernels.
//
// R12 -> R13: fix R12's spill regression, keep single-barrier ping-pong.
// R12 failed because af0+af1 both live -> frags 96 + acc 128 + addr > 256
// unified VGPR budget @ 2 waves/SIMD -> scratch spills (+45 MB HBM traffic,
// VALUBusy 11%). R13:
//  - af reused across A-quadrants (READ_A(CB,1) after MMA(0,1) consumed af)
//    -> frag liveness 64, total ~250 <= 256, no spills (R11 level).
//  - vmcnt drain moved to tile END: VM0 just before the closing BAR. The 8
//    stages issued at tile top have a full K-tile (~2500 cyc >> 900 cyc HBM
//    worst case) to land -> VM0 ~free, and BAR-after-VM0 makes cross-wave
//    stage visibility formally correct (R12's top-placed VM8 was race-y).
//  - counted LGKM(4) lets bq1 reads fly under MMA(0,0); compiler's own
//    dependency waitcnts guarantee correctness regardless of read order.
// One barrier per K-tile -> waves de-phase inside the tile; LDS pipe
// (~74k cyc/CU) overlaps MFMA pipe (~80k cyc/CU) instead of serializing.
// MFMA accumulation order bit-identical -> absmax unchanged (race detector).
// All other kernels unchanged.

using u16 = unsigned short;
using u32 = unsigned int;

typedef __bf16 bf16x8 __attribute__((ext_vector_type(8)));
typedef float  f32x4  __attribute__((ext_vector_type(4)));
typedef u32    u32x4  __attribute__((ext_vector_type(4)));
typedef u16    u16x4  __attribute__((ext_vector_type(4)));

#define DEVINL __device__ __forceinline__

DEVINL float b2f(u16 u) { union { u32 i; float f; } v; v.i = ((u32)u) << 16; return v.f; }
DEVINL u16 f2b(float f) {
  union { float f; u32 i; } v; v.f = f;
  u32 i = v.i;
  return (u16)((i + 0x7FFFu + ((i >> 16) & 1u)) >> 16);  // RNE; inputs are tame (no NaN)
}

#define L2E 1.4426950408889634f
#define LN2 0.6931471805599453f

// silu(a) = a/(1+e^-a) via HW exp2/rcp (1-ulp each; << bf16 quantization)
DEVINL float fast_silu(float a) {
  const float e = __builtin_amdgcn_exp2f(-a * L2E);
  return a * __builtin_amdgcn_rcpf(1.f + e);
}
// softplus(x) = ln(1+e^x) via HW exp2/log2; guard keeps large-x exact
DEVINL float fast_softplus(float x) {
  if (x > 20.f) return x;
  return LN2 * __builtin_amdgcn_logf(1.f + __builtin_amdgcn_exp2f(x * L2E));
}

DEVINL void gl_lds16(const u16* g, u16* l) {
  __builtin_amdgcn_global_load_lds(
      (__attribute__((address_space(1))) void*)const_cast<u16*>(g),
      (__attribute__((address_space(3))) void*)l, 16, 0, 0);
}

// ---------------------------------------------------------------------------
// 256x256 ping-pong GEMM (in_proj): C[m,n] = sum_k A[m,k]*B[n,k], bf16->f32.
// 512 threads = 8 waves; wave w owns rows (w>>2)*64, cols (w&3)*32 of each
// 128x128 C-quadrant. K-tile BK=64; buffers strictly alternate (ping-pong).
// LDS: A [0,64K) B [64K,128K), each: [buf][half(128rows)][row][64 bf16],
// swizzled colbyte ^= ((row&7)<<4).
// ---------------------------------------------------------------------------
#define BAR()    asm volatile("s_barrier" ::: "memory")
#define LGKM(N)  asm volatile("s_waitcnt lgkmcnt(" #N ")" ::: "memory")
#define VM0()    asm volatile("s_waitcnt vmcnt(0)" ::: "memory")
#define SCHB()   __builtin_amdgcn_sched_barrier(0)
#define NOPS     ((void)0)

__global__ __launch_bounds__(512, 2) void k_gemm256(
    const u16* __restrict__ A, int lda, int flipA,
    const u16* __restrict__ Bw, int ldb,
    u16* __restrict__ C, int ldc, int K)
{
  extern __shared__ __align__(16) char lds[];  // 131072 B

  const int tid  = threadIdx.x;
  const int lane = tid & 63;
  const int wid  = tid >> 6;

  const int mBase = blockIdx.x * 256;
  const int nBase = blockIdx.y * 256;

  // ---- staging: granule G = wid*128 + i*64 + lane (16 B each), row = G>>3,
  // slot = G&7; source col pre-swizzled so linear LDS + swizzled read match.
  const int rloc = lane >> 3;                       // 0..7
  const int scol = ((lane & 7) ^ rloc) << 3;        // elems (8 per granule)
  const u16* srcA[2][2];
  const u16* srcB[2][2];
#pragma unroll
  for (int h = 0; h < 2; ++h)
#pragma unroll
    for (int i = 0; i < 2; ++i) {
      int ra = mBase + h * 128 + wid * 16 + i * 8 + rloc;
      if (flipA) ra ^= 2047;                        // batch-local time flip
      const int rb = nBase + h * 128 + wid * 16 + i * 8 + rloc;
      srcA[h][i] = A  + (long long)ra * lda + scol;
      srcB[h][i] = Bw + (long long)rb * ldb + scol;
    }
  u16* const dA = (u16*)lds + wid * 1024;           // A region base, elems
  u16* const dB = (u16*)lds + 32768 + wid * 1024;   // B region base, elems

  // ---- ds_read byte offsets (within lds); swz makes every 16-lane group
  // cover all 8 16B-slots of a 128B row -> 2-way bank aliasing (free).
  const int lhi16 = (lane >> 4) * 16;
  const int swz   = (lane & 7) << 4;
  const int rdA   = ((wid >> 2) * 64 + (lane & 15)) * 128 + (lhi16 ^ swz);
  const int rdAx  = rdA ^ 64;                       // kk=1 (+32 elems)
  const int rdB   = 65536 + ((wid & 3) * 32 + (lane & 15)) * 128 + (lhi16 ^ swz);
  const int rdBx  = rdB ^ 64;

  f32x4 acc[2][2][4][2];
#pragma unroll
  for (int a = 0; a < 2; ++a)
#pragma unroll
    for (int b = 0; b < 2; ++b)
#pragma unroll
      for (int c = 0; c < 4; ++c)
#pragma unroll
        for (int d = 0; d < 2; ++d) acc[a][b][c][d] = (f32x4){0.f, 0.f, 0.f, 0.f};

  bf16x8 af[4][2], bq0[2][2], bq1[2][2];  // 64 frag VGPRs (af reused)

#define LDSV(off) (*(const bf16x8*)(lds + (off)))
#define READ_A(CB, QM, DST) do {                                               \
  _Pragma("unroll") for (int fm = 0; fm < 4; ++fm) {                           \
    DST[fm][0] = LDSV((CB)*32768 + (QM)*16384 + fm*2048 + rdA);                \
    DST[fm][1] = LDSV((CB)*32768 + (QM)*16384 + fm*2048 + rdAx); }             \
} while (0)
#define READ_B(CB, QN, DST) do {                                               \
  _Pragma("unroll") for (int fn = 0; fn < 2; ++fn) {                           \
    DST[fn][0] = LDSV((CB)*32768 + (QN)*16384 + fn*2048 + rdB);                \
    DST[fn][1] = LDSV((CB)*32768 + (QN)*16384 + fn*2048 + rdBx); }             \
} while (0)
#define MMA(QM, QN, AF, BFR) do {                                              \
  __builtin_amdgcn_s_setprio(1);                                              \
  _Pragma("unroll") for (int fm = 0; fm < 4; ++fm)                             \
  _Pragma("unroll") for (int fn = 0; fn < 2; ++fn)                             \
  _Pragma("unroll") for (int kk = 0; kk < 2; ++kk)                             \
    acc[QM][QN][fm][fn] = __builtin_amdgcn_mfma_f32_16x16x32_bf16(             \
        AF[fm][kk], BFR[fn][kk], acc[QM][QN][fm][fn], 0, 0, 0);                \
  __builtin_amdgcn_s_setprio(0);                                              \
} while (0)
// stage all 8 half-tiles of tile KT into buffer CB (A half0/1, B half0/1)
#define STAGE_ALL(CB, KT) do {                                                 \
  gl_lds16(srcA[0][0] + (KT)*64, dA + (CB)*16384);                             \
  gl_lds16(srcA[0][1] + (KT)*64, dA + (CB)*16384 + 512);                       \
  gl_lds16(srcA[1][0] + (KT)*64, dA + (CB)*16384 + 8192);                      \
  gl_lds16(srcA[1][1] + (KT)*64, dA + (CB)*16384 + 8192 + 512);                \
  gl_lds16(srcB[0][0] + (KT)*64, dB + (CB)*16384);                             \
  gl_lds16(srcB[0][1] + (KT)*64, dB + (CB)*16384 + 512);                       \
  gl_lds16(srcB[1][0] + (KT)*64, dB + (CB)*16384 + 8192);                      \
  gl_lds16(srcB[1][1] + (KT)*64, dB + (CB)*16384 + 8192 + 512);                \
} while (0)

// one K-tile: stage next tile into CB^1 (top), read CB with af-reuse phases,
// MFMA gated by counted lgkm (compiler also inserts precise dep-waits).
// VM0 at tile END is ~free (stages had a whole K-tile to land) and makes
// cross-wave stage visibility correct before the single closing barrier.
#define KTILE2(CB, STG) do {                                                   \
  STG;                                                                         \
  READ_A(CB, 0, af); READ_B(CB, 0, bq0); READ_B(CB, 1, bq1);                   \
  LGKM(4); SCHB();                                                             \
  MMA(0, 0, af, bq0);                                                          \
  LGKM(0); SCHB();                                                             \
  MMA(0, 1, af, bq1);                                                          \
  READ_A(CB, 1, af);                                                           \
  LGKM(0); SCHB();                                                             \
  MMA(1, 1, af, bq1);                                                          \
  MMA(1, 0, af, bq0);                                                          \
  VM0(); BAR();                                                                \
} while (0)

  // prologue: tile 0 -> buf0; VM0+BAR = all waves' stages landed & visible.
  STAGE_ALL(0, 0);
  VM0(); BAR();

  // K = 1024 -> 16 K-tiles; 14 in the steady loop + 2 peeled tail tiles.
  for (int it = 0; it < 7; ++it) {
    const int kt = 2 * it;
    KTILE2(0, STAGE_ALL(1, kt + 1));
    KTILE2(1, STAGE_ALL(0, kt + 2));
  }
  KTILE2(0, STAGE_ALL(1, 15));
  KTILE2(1, NOPS);

  // epilogue: D mapping col = lane&15, row = (lane>>4)*4 + reg  [m89]
  const int rq = (lane >> 4) << 2;
  const int cn = lane & 15;
  const long long mW = mBase + (wid >> 2) * 64;
  const int nW = nBase + (wid & 3) * 32;
#pragma unroll
  for (int qm = 0; qm < 2; ++qm)
#pragma unroll
    for (int qn = 0; qn < 2; ++qn)
#pragma unroll
      for (int fm = 0; fm < 4; ++fm)
#pragma unroll
        for (int fn = 0; fn < 2; ++fn)
#pragma unroll
          for (int r = 0; r < 4; ++r) {
            const long long m = mW + qm * 128 + fm * 16 + rq + r;
            const int n = nW + qn * 128 + fn * 16 + cn;
            C[m * ldc + n] = f2b(acc[qm][qn][fm][fn][r]);
          }
#undef LDSV
#undef READ_A
#undef READ_B
#undef MMA
#undef STAGE_ALL
#undef KTILE2
}

// ---------------------------------------------------------------------------
// GEMM: C[m,n] = sum_k A[m,k] * B[n,k]   (both K-major, bf16 in, fp32 acc)
// 128x128 tile, BK=64, 256 threads (4 waves, each 64x64 = 4x4 mfma 16x16x32).
// MODE 1: softplus(acc + f1[n]) -> bf16
// MODE 2: store fp32              MODE 3: fp32 store to out2 at m^2047, += f2
// MODE 4: n<64 -> bf16 Cout; n in [64,96) -> split fp32 to f1(B)/f2(C)
// ---------------------------------------------------------------------------
template <int MODE>
__global__ __launch_bounds__(256) void k_gemm(
    const u16* __restrict__ A, int lda, int flipA,
    const u16* __restrict__ Bw, int ldb,
    void* __restrict__ Cout, int ldc, int K,
    float* __restrict__ f1, float* __restrict__ f2,
    float* __restrict__ out2)
{
  __shared__ __align__(16) u16 As[128 * 64];
  __shared__ __align__(16) u16 Bs[128 * 64];

  const int tid  = threadIdx.x;
  const int lane = tid & 63;
  const int wid  = tid >> 6;

  const int mBase = blockIdx.x * 128;
  const int nBase = blockIdx.y * 128;

  f32x4 acc[4][4];
#pragma unroll
  for (int i = 0; i < 4; ++i)
#pragma unroll
    for (int j = 0; j < 4; ++j) acc[i][j] = (f32x4){0.f, 0.f, 0.f, 0.f};

  const int wm = (wid & 1) * 64;
  const int wn = (wid >> 1) * 64;
  const int lrow = lane & 15;
  const int lk   = (lane >> 4) * 8;
  const int sr = tid >> 3;         // staging row within 32-row group [0,32)
  const int sc = (tid & 7) * 8;    // staging col (8 bf16 = 16 B)

  for (int k0 = 0; k0 < K; k0 += 64) {
#pragma unroll
    for (int i = 0; i < 4; ++i) {
      int ra = mBase + i * 32 + sr;
      if (flipA) ra ^= 2047;               // SGPR-uniform time flip
      const int rb = nBase + i * 32 + sr;
      u16* la = &As[(i * 256 + wid * 64) * 8];
      u16* lb = &Bs[(i * 256 + wid * 64) * 8];
      gl_lds16(A  + (long long)ra * lda + (k0 + sc), la);
      gl_lds16(Bw + (long long)rb * ldb + (k0 + sc), lb);
    }
    __syncthreads();
#pragma unroll
    for (int kk = 0; kk < 64; kk += 32) {
      bf16x8 af[4], bfr[4];
#pragma unroll
      for (int f = 0; f < 4; ++f) {
        af[f]  = *(const bf16x8*)&As[(wm + f * 16 + lrow) * 64 + kk + lk];
        bfr[f] = *(const bf16x8*)&Bs[(wn + f * 16 + lrow) * 64 + kk + lk];
      }
#pragma unroll
      for (int fm = 0; fm < 4; ++fm)
#pragma unroll
        for (int fn = 0; fn < 4; ++fn)
          acc[fm][fn] = __builtin_amdgcn_mfma_f32_16x16x32_bf16(af[fm], bfr[fn], acc[fm][fn], 0, 0, 0);
    }
    __syncthreads();
  }

  const int rowq = (lane >> 4) * 4;
  const int coln = lane & 15;
#pragma unroll
  for (int fm = 0; fm < 4; ++fm) {
#pragma unroll
    for (int fn = 0; fn < 4; ++fn) {
#pragma unroll
      for (int r = 0; r < 4; ++r) {
        const long long m = mBase + wm + fm * 16 + rowq + r;
        const long long n = nBase + wn + fn * 16 + coln;
        const float v = acc[fm][fn][r];
        if constexpr (MODE == 0) {
          ((u16*)Cout)[m * ldc + n] = f2b(v);
        } else if constexpr (MODE == 1) {
          ((u16*)Cout)[m * ldc + n] = f2b(fast_softplus(v + f1[(int)n]));
        } else if constexpr (MODE == 2) {
          ((float*)Cout)[m * ldc + n] = v;
        } else if constexpr (MODE == 3) {
          const long long mf = m ^ 2047;  // time flip within batch (L=2048)
          out2[mf * ldc + n] = v + f2[mf * ldc + n];
        } else {  // MODE 4 (x_proj): dt-raw -> proj bf16; B/C -> fp32 split
          if (n < 64)       ((u16*)Cout)[m * ldc + n] = f2b(v);
          else if (n < 80)  f1[m * 16 + (n - 64)] = v;
          else if (n < 96)  f2[m * 16 + (n - 80)] = v;
        }
      }
    }
  }
}

// ---------------------------------------------------------------------------
// fused per-dir prep: [0,4096) castw inw | [4096,5120) pad+cast xw |
// [5120,5248) castw dtw | [5248,5376) A2 | [5376,5408) cwT transpose
// ---------------------------------------------------------------------------
__global__ __launch_bounds__(256) void k_prep(
    const float* __restrict__ inw_d, u16* __restrict__ inwB,
    const float* __restrict__ xpw_d, u16* __restrict__ xw_pad,
    const float* __restrict__ dtw_d, u16* __restrict__ dtwB,
    const float* __restrict__ alog_d, float* __restrict__ A2,
    const float* __restrict__ cw_d, float* __restrict__ cwT)
{
  const int bx = blockIdx.x;
  const int tid = threadIdx.x;
  if (bx < 4096) {
    const int i = bx * 256 + tid;
    const f32x4 v = ((const f32x4*)inw_d)[i];
    u16x4 o = {f2b(v[0]), f2b(v[1]), f2b(v[2]), f2b(v[3])};
    ((u16x4*)inwB)[i] = o;
  } else if (bx < 5120) {
    const int idx = (bx - 4096) * 256 + tid;  // [0, 128*2048)
    const int c = idx & 2047, r = idx >> 11;
    xw_pad[idx] = (r < 96) ? f2b(xpw_d[r * 2048 + c]) : (u16)0;
  } else if (bx < 5248) {
    const int i = (bx - 5120) * 256 + tid;    // 2048*64/4
    const f32x4 v = ((const f32x4*)dtw_d)[i];
    u16x4 o = {f2b(v[0]), f2b(v[1]), f2b(v[2]), f2b(v[3])};
    ((u16x4*)dtwB)[i] = o;
  } else if (bx < 5376) {
    const int idx = (bx - 5248) * 256 + tid;  // [0, 2048*16)
    A2[idx] = -expf(alog_d[idx]) * L2E;  // A * log2(e)
  } else {
    const int idx = (bx - 5376) * 256 + tid;  // [0, 8192)
    const int d = idx & 2047, k = idx >> 11;
    cwT[k * 2048 + d] = cw_d[d * 4 + k];      // [2048][4] -> [4][2048]
  }
}

__global__ __launch_bounds__(256) void k_castw(const float* __restrict__ src,
                                               u16* __restrict__ dst) {
  const int i = blockIdx.x * 256 + threadIdx.x;
  const f32x4 v = ((const f32x4*)src)[i];
  u16x4 o = {f2b(v[0]), f2b(v[1]), f2b(v[2]), f2b(v[3])};
  ((u16x4*)dst)[i] = o;
}

// x fp32 [4][2048][1024] -> bf16 (no flip; dir1 flip happens in GEMM staging)
__global__ __launch_bounds__(256) void k_cast_x(const float* __restrict__ x,
                                                u16* __restrict__ xA) {
  const int idx = blockIdx.x * 256 + threadIdx.x;  // [0, 4*2048*256)
  const f32x4 v = ((const f32x4*)x)[idx];
  u16x4 o = {f2b(v[0]), f2b(v[1]), f2b(v[2]), f2b(v[3])};
  ((u16x4*)xA)[idx] = o;
}

// ---------------------------------------------------------------------------
// depthwise causal conv (k=4) + bias + silu.  xi lives in xz cols [0,2048).
// ---------------------------------------------------------------------------
__global__ __launch_bounds__(256) void k_conv(const u16* __restrict__ xz,
                                              const float* __restrict__ cwT,
                                              const float* __restrict__ cb,
                                              u16* __restrict__ xc) {
  const int idx = blockIdx.x * 256 + threadIdx.x;  // [0, 8192*256)
  const int d8  = idx & 255;
  const int gr  = idx >> 8;
  const int t   = gr & 2047;
  const int d0  = d8 * 8;

  float acc[8];
  {
    const f32x4 b0 = *(const f32x4*)(cb + d0);
    const f32x4 b1 = *(const f32x4*)(cb + d0 + 4);
#pragma unroll
    for (int j = 0; j < 4; ++j) { acc[j] = b0[j]; acc[4 + j] = b1[j]; }
  }

#pragma unroll
  for (int k = 0; k < 4; ++k) {
    const int tt = t - 3 + k;
    if (tt < 0) continue;
    const u32x4 v = *(const u32x4*)(xz + (long long)(gr + k - 3) * 4096 + d0);
    const u16* pv = (const u16*)&v;
    const f32x4 w0 = *(const f32x4*)(cwT + k * 2048 + d0);
    const f32x4 w1 = *(const f32x4*)(cwT + k * 2048 + d0 + 4);
#pragma unroll
    for (int j = 0; j < 4; ++j) {
      acc[j]     = fmaf(w0[j], b2f(pv[j]), acc[j]);
      acc[4 + j] = fmaf(w1[j], b2f(pv[4 + j]), acc[4 + j]);
    }
  }
  u16 o[8];
#pragma unroll
  for (int j = 0; j < 8; ++j) {
    o[j] = f2b(fast_silu(acc[j]));
  }
  *(u32x4*)(xc + (long long)gr * 2048 + d0) = *(const u32x4*)o;
}

// ---------------------------------------------------------------------------
// scan phase A: per-chunk local scan (h from 0), CHUNK=64. Writes ONLY chunk
// summaries hbuf[b][c][s][d] (local end-state) and sumdt[b][c][d].
// grid: 4(b) * 32(chunk) * 8(dchunk) = 1024 blocks
// ---------------------------------------------------------------------------
__global__ __launch_bounds__(256) void k_scanA(
    const u16* __restrict__ dt, const u16* __restrict__ xc,
    const float* __restrict__ Bf, const float* __restrict__ A2,
    float* __restrict__ hbuf, float* __restrict__ sumdt)
{
  const int tid = threadIdx.x;
  const int bx  = blockIdx.x;
  const int d     = (bx & 7) * 256 + tid;
  const int chunk = (bx >> 3) & 31;
  const int b     = bx >> 8;

  float a2[16];
#pragma unroll
  for (int s = 0; s < 16; ++s) a2[s] = A2[d * 16 + s];

  float h[16];
#pragma unroll
  for (int s = 0; s < 16; ++s) h[s] = 0.f;
  float sdt = 0.f;

  const long long rowBase = (long long)b * 2048 + chunk * 64;
  for (int t0 = 0; t0 < 64; ++t0) {
    const long long gr = rowBase + t0;
    const float dtv = b2f(dt[gr * 2048 + d]);
    const float xcv = b2f(xc[gr * 2048 + d]);
    sdt += dtv;
    const float dtx = dtv * xcv;
    float Bv[16];
    *(f32x4*)&Bv[0]  = *(const f32x4*)(Bf + gr * 16);
    *(f32x4*)&Bv[4]  = *(const f32x4*)(Bf + gr * 16 + 4);
    *(f32x4*)&Bv[8]  = *(const f32x4*)(Bf + gr * 16 + 8);
    *(f32x4*)&Bv[12] = *(const f32x4*)(Bf + gr * 16 + 12);
#pragma unroll
    for (int s = 0; s < 16; ++s) {
      const float dA = __builtin_amdgcn_exp2f(a2[s] * dtv);
      h[s] = fmaf(h[s], dA, dtx * Bv[s]);
    }
  }
  const long long cbi = (long long)b * 32 + chunk;
#pragma unroll
  for (int s = 0; s < 16; ++s) hbuf[(cbi * 16 + s) * 2048 + d] = h[s];
  sumdt[cbi * 2048 + d] = sdt;
}

// phase B: chain chunk states IN PLACE: hbuf[c] goes local-end-state ->
// entering-state. s-chains are independent -> split x2 (8 s per block).
// grid: 4(b) * 8(dchunk) * 2(sgroup) = 64 blocks
__global__ __launch_bounds__(256) void k_scanB(
    const float* __restrict__ A2, float* __restrict__ hbuf,
    const float* __restrict__ sumdt)
{
  const int tid = threadIdx.x;
  const int bx  = blockIdx.x;
  const int d   = (bx & 7) * 256 + tid;
  const int sg  = ((bx >> 3) & 1) * 8;
  const int b   = bx >> 4;

  float a2[8];
#pragma unroll
  for (int s = 0; s < 8; ++s) a2[s] = A2[d * 16 + sg + s];
  float h[8];
#pragma unroll
  for (int s = 0; s < 8; ++s) h[s] = 0.f;

  const long long base = (long long)b * 32;
  for (int c = 0; c < 32; ++c) {
    const long long cbi = base + c;
    const float sd = sumdt[cbi * 2048 + d];
#pragma unroll
    for (int s = 0; s < 8; ++s) {
      float* p = &hbuf[(cbi * 16 + sg + s) * 2048 + d];
      const float loc = *p;      // local end-state of chunk c
      *p = h[s];                 // replace with state ENTERING chunk c
      const float P = __builtin_amdgcn_exp2f(a2[s] * sd);
      h[s] = fmaf(h[s], P, loc);
    }
  }
}

// ---------------------------------------------------------------------------
// phase C: true recurrence from entering state + gate, y written once.
// y = h.C with h = h*dA + dtx*B stepped from hbuf state; then
// y_fin = (y + xc*Dp) * silu(z). grid 1024 (same decomposition as A).
// ---------------------------------------------------------------------------
__global__ __launch_bounds__(256) void k_scanC(
    const u16* __restrict__ dt, const u16* __restrict__ xc,
    const float* __restrict__ Bf, const float* __restrict__ Cf,
    const float* __restrict__ A2, const float* __restrict__ hbuf,
    const float* __restrict__ Dp, u16* __restrict__ yz)
{
  const int tid = threadIdx.x;
  const int bx  = blockIdx.x;
  const int d     = (bx & 7) * 256 + tid;
  const int chunk = (bx >> 3) & 31;
  const int b     = bx >> 8;
  const float dp  = Dp[d];

  float a2[16];
#pragma unroll
  for (int s = 0; s < 16; ++s) a2[s] = A2[d * 16 + s];

  const long long cbi = (long long)b * 32 + chunk;
  float h[16];
#pragma unroll
  for (int s = 0; s < 16; ++s) h[s] = hbuf[(cbi * 16 + s) * 2048 + d];

  const long long rowBase = (long long)b * 2048 + chunk * 64;
  for (int t0 = 0; t0 < 64; ++t0) {
    const long long gr = rowBase + t0;
    const float dtv = b2f(dt[gr * 2048 + d]);
    const float xcv = b2f(xc[gr * 2048 + d]);
    const float dtx = dtv * xcv;
    float Bv[16], Cv[16];
    *(f32x4*)&Bv[0]  = *(const f32x4*)(Bf + gr * 16);
    *(f32x4*)&Bv[4]  = *(const f32x4*)(Bf + gr * 16 + 4);
    *(f32x4*)&Bv[8]  = *(const f32x4*)(Bf + gr * 16 + 8);
    *(f32x4*)&Bv[12] = *(const f32x4*)(Bf + gr * 16 + 12);
    *(f32x4*)&Cv[0]  = *(const f32x4*)(Cf + gr * 16);
    *(f32x4*)&Cv[4]  = *(const f32x4*)(Cf + gr * 16 + 4);
    *(f32x4*)&Cv[8]  = *(const f32x4*)(Cf + gr * 16 + 8);
    *(f32x4*)&Cv[12] = *(const f32x4*)(Cf + gr * 16 + 12);
    float y = 0.f;
#pragma unroll
    for (int s = 0; s < 16; ++s) {
      const float dA = __builtin_amdgcn_exp2f(a2[s] * dtv);
      h[s] = fmaf(h[s], dA, dtx * Bv[s]);
      y = fmaf(h[s], Cv[s], y);
    }
    const float z = b2f(yz[gr * 4096 + 2048 + d]);
    const float yv = (y + xcv * dp) * fast_silu(z);
    yz[gr * 4096 + d] = f2b(yv);
  }
}

// ---------------------------------------------------------------------------
extern "C" void kernel_launch(void* const* d_in, const int* in_sizes, int n_in,
                              void* d_out, int out_size, void* d_ws, size_t ws_size,
                              hipStream_t stream) {
  const float* x    = (const float*)d_in[0];
  const float* inw  = (const float*)d_in[1];
  const float* cw   = (const float*)d_in[2];
  const float* cb   = (const float*)d_in[3];
  const float* xpw  = (const float*)d_in[4];
  const float* dtw  = (const float*)d_in[5];
  const float* dtb  = (const float*)d_in[6];
  const float* alog = (const float*)d_in[7];
  const float* Dp   = (const float*)d_in[8];
  const float* ow   = (const float*)d_in[9];
  float* out = (float*)d_out;

  // workspace layout (bytes) — per-direction buffers reused across dir 0/1.
  char* ws = (char*)d_ws;
  float* outacc = (float*)(ws + 0);          //  33,554,432  [8192][1024] fp32
  u16*   xz_d   = (u16*)(ws + 33554432);     //  67,108,864  [8192][4096] xi|z -> y|z
  u16*   xc_d   = (u16*)(ws + 100663296);    //  33,554,432  [8192][2048]
  u16*   inwB   = (u16*)(ws + 100663296);    //   8,388,608  (xc dead during in_proj)
  u16*   dt_d   = (u16*)(ws + 134217728);    //  33,554,432  [8192][2048]
  u16*   owB    = (u16*)(ws + 134217728);    //   4,194,304  (dt dead after scanC)
  u16*   xA     = (u16*)(ws + 167772160);    //  16,777,216  [8192][1024] persistent
  u16*   proj_d = (u16*)(ws + 184549376);    //   1,048,576  [8192][64] (stride 64)
  u16*   xw_pad = (u16*)(ws + 185597952);    //     524,288  [128][2048]
  float* A2     = (float*)(ws + 186122240);  //     131,072  [2048][16]
  float* Bf     = (float*)(ws + 186253312);  //     524,288  [8192][16]
  float* Cf     = (float*)(ws + 186777600);  //     524,288
  float* hbuf   = (float*)(ws + 187301888);  //  16,777,216  [4][32][16][2048] in-place
  float* sumdt  = (float*)(ws + 204079104);  //   1,048,576  [4][32][2048]
  u16*   dtwB   = (u16*)(ws + 205127680);    //     262,144  [2048][64]
  float* cwT    = (float*)(ws + 205389824);  //      32,768  [4][2048]
  const size_t NEED = 205422592;  // <= 205,651,968 proven available (R2 ran)

  (void)in_sizes; (void)n_in; (void)out_size;
  if (ws_size < NEED) {  // deterministic guard: leaves d_out zeroed -> clean fail
    fprintf(stderr, "[BiMamba] ws_size=%zu < needed %zu — aborting launch\n", ws_size, NEED);
    return;
  }

  // allow 128 KiB dynamic LDS for the ping-pong GEMM (host-side, capture-safe)
  static bool attr_set = false;
  if (!attr_set) {
    (void)hipFuncSetAttribute((const void*)k_gemm256,
                              hipFuncAttributeMaxDynamicSharedMemorySize, 131072);
    attr_set = true;
  }

  k_cast_x<<<8192, 256, 0, stream>>>(x, xA);  // once; dir1 flips in staging

  for (int dir = 0; dir < 2; ++dir) {
    const float* inw_d = inw + (long long)dir * 4096 * 1024;
    const float* cw_d  = cw  + dir * 2048 * 4;
    const float* cb_d  = cb  + dir * 2048;
    const float* xpw_d = xpw + dir * 96 * 2048;
    const float* dtw_d = dtw + dir * 2048 * 64;
    const float* dtb_d = dtb + dir * 2048;
    const float* al_d  = alog + dir * 2048 * 16;
    const float* Dp_d  = Dp  + dir * 2048;
    const float* ow_d  = ow  + (long long)dir * 1024 * 2048;

    k_prep<<<5408, 256, 0, stream>>>(inw_d, inwB, xpw_d, xw_pad,
                                     dtw_d, dtwB, al_d, A2, cw_d, cwT);

    // in_proj: xz = xA[8192,1024] x inwB[4096,1024]^T  (dir1: A rows ^2047)
    // 256^2 ping-pong template, 512 thr, 128 KiB LDS
    k_gemm256<<<dim3(32, 16), 512, 131072, stream>>>(
        xA, 1024, dir, inwB, 1024, xz_d, 4096, 1024);

    k_conv<<<8192, 256, 0, stream>>>(xz_d, cwT, cb_d, xc_d);

    // x_proj: proj(dt-raw, stride 64) + Bf/Cf fp32 split, fused epilogue
    k_gemm<4><<<dim3(64, 1), 256, 0, stream>>>(
        xc_d, 2048, 0, xw_pad, 2048, proj_d, 64, 2048, Bf, Cf, nullptr);

    // dt_proj: dt = softplus(proj[8192,64] x dtwB[2048,64]^T + dtb)
    k_gemm<1><<<dim3(64, 16), 256, 0, stream>>>(
        proj_d, 64, 0, dtwB, 64, dt_d, 2048, 64,
        const_cast<float*>(dtb_d), nullptr, nullptr);

    k_scanA<<<1024, 256, 0, stream>>>(dt_d, xc_d, Bf, A2, hbuf, sumdt);
    k_scanB<<<64, 256, 0, stream>>>(A2, hbuf, sumdt);
    k_scanC<<<1024, 256, 0, stream>>>(dt_d, xc_d, Bf, Cf, A2, hbuf, Dp_d, xz_d);

    // out_proj weights -> bf16 (dt region dead after scanC)
    k_castw<<<2048, 256, 0, stream>>>(ow_d, owB);

    if (dir == 0) {
      k_gemm<2><<<dim3(64, 8), 256, 0, stream>>>(
          xz_d, 4096, 0, owB, 2048, outacc, 1024, 2048, nullptr, nullptr, nullptr);
    } else {
      k_gemm<3><<<dim3(64, 8), 256, 0, stream>>>(
          xz_d, 4096, 0, owB, 2048, nullptr, 1024, 2048,
          nullptr, outacc, out);
    }
  }
}

// Round 7
// 741.367 us; speedup vs baseline: 1.1664x; 1.0619x over previous
//
#include <hip/hip_runtime.h>
#include <hip/hip_bf16.h>
#include <math.h>
#include <stdio.h>

// BiMambaBlock: bidirectional Mamba forward.
// B=4, L=2048, D_MODEL=1024, D_INNER=2048, D_STATE=16, D_CONV=4, DT_RANK=64.
// Inputs/output fp32; GEMMs run bf16 MFMA (fp32 acc) via cast kernels.
//
// R13 -> R14: out_proj moved off the 128^2 2-barrier structure (~613 TF,
// ~56us/dir) onto a 256x128-tile single-barrier ping-pong kernel (k_gemmOut),
// same verified schedule/swizzle family as R13's in_proj:
//  - grid (32,8) = 256 blocks = 1/CU, full chip in one round (N=1024 makes
//    256^2 tiles infeasible: only 128 blocks -> half chip idle).
//  - 8 waves as 4m x 2n, each 64x64 out -> acc 64 VGPR/lane (no spill risk),
//    af/bfr 64 more, ~160 total.
//  - LDS 96 KiB: A[2][256][64] + B[2][128][64], st-swizzle unchanged
//    (row&7 == lane&7 carries over), 16 ds_reads + 32 MFMA /wave/K-tile.
//  - one VM0+barrier per K-tile (stages at tile top -> whole tile to land).
// Per-element K-accumulation order identical -> absmax unchanged.
// in_proj (R13 k_gemm256) and all other kernels unchanged.

using u16 = unsigned short;
using u32 = unsigned int;

typedef __bf16 bf16x8 __attribute__((ext_vector_type(8)));
typedef float  f32x4  __attribute__((ext_vector_type(4)));
typedef u32    u32x4  __attribute__((ext_vector_type(4)));
typedef u16    u16x4  __attribute__((ext_vector_type(4)));

#define DEVINL __device__ __forceinline__

DEVINL float b2f(u16 u) { union { u32 i; float f; } v; v.i = ((u32)u) << 16; return v.f; }
DEVINL u16 f2b(float f) {
  union { float f; u32 i; } v; v.f = f;
  u32 i = v.i;
  return (u16)((i + 0x7FFFu + ((i >> 16) & 1u)) >> 16);  // RNE; inputs are tame (no NaN)
}

#define L2E 1.4426950408889634f
#define LN2 0.6931471805599453f

// silu(a) = a/(1+e^-a) via HW exp2/rcp (1-ulp each; << bf16 quantization)
DEVINL float fast_silu(float a) {
  const float e = __builtin_amdgcn_exp2f(-a * L2E);
  return a * __builtin_amdgcn_rcpf(1.f + e);
}
// softplus(x) = ln(1+e^x) via HW exp2/log2; guard keeps large-x exact
DEVINL float fast_softplus(float x) {
  if (x > 20.f) return x;
  return LN2 * __builtin_amdgcn_logf(1.f + __builtin_amdgcn_exp2f(x * L2E));
}

DEVINL void gl_lds16(const u16* g, u16* l) {
  __builtin_amdgcn_global_load_lds(
      (__attribute__((address_space(1))) void*)const_cast<u16*>(g),
      (__attribute__((address_space(3))) void*)l, 16, 0, 0);
}

#define BAR()    asm volatile("s_barrier" ::: "memory")
#define LGKM(N)  asm volatile("s_waitcnt lgkmcnt(" #N ")" ::: "memory")
#define VM0()    asm volatile("s_waitcnt vmcnt(0)" ::: "memory")
#define SCHB()   __builtin_amdgcn_sched_barrier(0)
#define NOPS     ((void)0)

// ---------------------------------------------------------------------------
// 256x256 ping-pong GEMM (in_proj): C[m,n] = sum_k A[m,k]*B[n,k], bf16->f32.
// 512 threads = 8 waves; wave w owns rows (w>>2)*64, cols (w&3)*32 of each
// 128x128 C-quadrant. K-tile BK=64; buffers strictly alternate (ping-pong).
// LDS: A [0,64K) B [64K,128K), each: [buf][half(128rows)][row][64 bf16],
// swizzled colbyte ^= ((row&7)<<4).
// ---------------------------------------------------------------------------
__global__ __launch_bounds__(512, 2) void k_gemm256(
    const u16* __restrict__ A, int lda, int flipA,
    const u16* __restrict__ Bw, int ldb,
    u16* __restrict__ C, int ldc, int K)
{
  extern __shared__ __align__(16) char lds[];  // 131072 B

  const int tid  = threadIdx.x;
  const int lane = tid & 63;
  const int wid  = tid >> 6;

  const int mBase = blockIdx.x * 256;
  const int nBase = blockIdx.y * 256;

  // ---- staging: granule G = wid*128 + i*64 + lane (16 B each), row = G>>3,
  // slot = G&7; source col pre-swizzled so linear LDS + swizzled read match.
  const int rloc = lane >> 3;                       // 0..7
  const int scol = ((lane & 7) ^ rloc) << 3;        // elems (8 per granule)
  const u16* srcA[2][2];
  const u16* srcB[2][2];
#pragma unroll
  for (int h = 0; h < 2; ++h)
#pragma unroll
    for (int i = 0; i < 2; ++i) {
      int ra = mBase + h * 128 + wid * 16 + i * 8 + rloc;
      if (flipA) ra ^= 2047;                        // batch-local time flip
      const int rb = nBase + h * 128 + wid * 16 + i * 8 + rloc;
      srcA[h][i] = A  + (long long)ra * lda + scol;
      srcB[h][i] = Bw + (long long)rb * ldb + scol;
    }
  u16* const dA = (u16*)lds + wid * 1024;           // A region base, elems
  u16* const dB = (u16*)lds + 32768 + wid * 1024;   // B region base, elems

  // ---- ds_read byte offsets (within lds); swz makes every 16-lane group
  // cover all 8 16B-slots of a 128B row -> 2-way bank aliasing (free).
  const int lhi16 = (lane >> 4) * 16;
  const int swz   = (lane & 7) << 4;
  const int rdA   = ((wid >> 2) * 64 + (lane & 15)) * 128 + (lhi16 ^ swz);
  const int rdAx  = rdA ^ 64;                       // kk=1 (+32 elems)
  const int rdB   = 65536 + ((wid & 3) * 32 + (lane & 15)) * 128 + (lhi16 ^ swz);
  const int rdBx  = rdB ^ 64;

  f32x4 acc[2][2][4][2];
#pragma unroll
  for (int a = 0; a < 2; ++a)
#pragma unroll
    for (int b = 0; b < 2; ++b)
#pragma unroll
      for (int c = 0; c < 4; ++c)
#pragma unroll
        for (int d = 0; d < 2; ++d) acc[a][b][c][d] = (f32x4){0.f, 0.f, 0.f, 0.f};

  bf16x8 af[4][2], bq0[2][2], bq1[2][2];  // 64 frag VGPRs (af reused)

#define LDSV(off) (*(const bf16x8*)(lds + (off)))
#define READ_A(CB, QM, DST) do {                                               \
  _Pragma("unroll") for (int fm = 0; fm < 4; ++fm) {                           \
    DST[fm][0] = LDSV((CB)*32768 + (QM)*16384 + fm*2048 + rdA);                \
    DST[fm][1] = LDSV((CB)*32768 + (QM)*16384 + fm*2048 + rdAx); }             \
} while (0)
#define READ_B(CB, QN, DST) do {                                               \
  _Pragma("unroll") for (int fn = 0; fn < 2; ++fn) {                           \
    DST[fn][0] = LDSV((CB)*32768 + (QN)*16384 + fn*2048 + rdB);                \
    DST[fn][1] = LDSV((CB)*32768 + (QN)*16384 + fn*2048 + rdBx); }             \
} while (0)
#define MMA(QM, QN, AF, BFR) do {                                              \
  __builtin_amdgcn_s_setprio(1);                                              \
  _Pragma("unroll") for (int fm = 0; fm < 4; ++fm)                             \
  _Pragma("unroll") for (int fn = 0; fn < 2; ++fn)                             \
  _Pragma("unroll") for (int kk = 0; kk < 2; ++kk)                             \
    acc[QM][QN][fm][fn] = __builtin_amdgcn_mfma_f32_16x16x32_bf16(             \
        AF[fm][kk], BFR[fn][kk], acc[QM][QN][fm][fn], 0, 0, 0);                \
  __builtin_amdgcn_s_setprio(0);                                              \
} while (0)
// stage all 8 half-tiles of tile KT into buffer CB (A half0/1, B half0/1)
#define STAGE_ALL(CB, KT) do {                                                 \
  gl_lds16(srcA[0][0] + (KT)*64, dA + (CB)*16384);                             \
  gl_lds16(srcA[0][1] + (KT)*64, dA + (CB)*16384 + 512);                       \
  gl_lds16(srcA[1][0] + (KT)*64, dA + (CB)*16384 + 8192);                      \
  gl_lds16(srcA[1][1] + (KT)*64, dA + (CB)*16384 + 8192 + 512);                \
  gl_lds16(srcB[0][0] + (KT)*64, dB + (CB)*16384);                             \
  gl_lds16(srcB[0][1] + (KT)*64, dB + (CB)*16384 + 512);                       \
  gl_lds16(srcB[1][0] + (KT)*64, dB + (CB)*16384 + 8192);                      \
  gl_lds16(srcB[1][1] + (KT)*64, dB + (CB)*16384 + 8192 + 512);                \
} while (0)

// one K-tile: stage next tile into CB^1 (top), read CB with af-reuse phases,
// MFMA gated by counted lgkm (compiler also inserts precise dep-waits).
// VM0 at tile END is ~free (stages had a whole K-tile to land) and makes
// cross-wave stage visibility correct before the single closing barrier.
#define KTILE2(CB, STG) do {                                                   \
  STG;                                                                         \
  READ_A(CB, 0, af); READ_B(CB, 0, bq0); READ_B(CB, 1, bq1);                   \
  LGKM(4); SCHB();                                                             \
  MMA(0, 0, af, bq0);                                                          \
  LGKM(0); SCHB();                                                             \
  MMA(0, 1, af, bq1);                                                          \
  READ_A(CB, 1, af);                                                           \
  LGKM(0); SCHB();                                                             \
  MMA(1, 1, af, bq1);                                                          \
  MMA(1, 0, af, bq0);                                                          \
  VM0(); BAR();                                                                \
} while (0)

  // prologue: tile 0 -> buf0; VM0+BAR = all waves' stages landed & visible.
  STAGE_ALL(0, 0);
  VM0(); BAR();

  // K = 1024 -> 16 K-tiles; 14 in the steady loop + 2 peeled tail tiles.
  for (int it = 0; it < 7; ++it) {
    const int kt = 2 * it;
    KTILE2(0, STAGE_ALL(1, kt + 1));
    KTILE2(1, STAGE_ALL(0, kt + 2));
  }
  KTILE2(0, STAGE_ALL(1, 15));
  KTILE2(1, NOPS);

  // epilogue: D mapping col = lane&15, row = (lane>>4)*4 + reg  [m89]
  const int rq = (lane >> 4) << 2;
  const int cn = lane & 15;
  const long long mW = mBase + (wid >> 2) * 64;
  const int nW = nBase + (wid & 3) * 32;
#pragma unroll
  for (int qm = 0; qm < 2; ++qm)
#pragma unroll
    for (int qn = 0; qn < 2; ++qn)
#pragma unroll
      for (int fm = 0; fm < 4; ++fm)
#pragma unroll
        for (int fn = 0; fn < 2; ++fn)
#pragma unroll
          for (int r = 0; r < 4; ++r) {
            const long long m = mW + qm * 128 + fm * 16 + rq + r;
            const int n = nW + qn * 128 + fn * 16 + cn;
            C[m * ldc + n] = f2b(acc[qm][qn][fm][fn][r]);
          }
#undef LDSV
#undef READ_A
#undef READ_B
#undef MMA
#undef STAGE_ALL
#undef KTILE2
}

// ---------------------------------------------------------------------------
// 256x128 ping-pong GEMM (out_proj): same schedule family as k_gemm256.
// 512 threads = 8 waves as 4m x 2n; wave owns 64x64. K-tile BK=64.
// LDS 96 KiB: A[2][256][64] at byte 0, B[2][128][64] at byte 65536,
// swizzled colbyte ^= ((row&7)<<4). One VM0+barrier per K-tile.
// MODE 2: fp32 store to Cout.  MODE 3: out2[m^2047][n] = v + f2[m^2047][n].
// ---------------------------------------------------------------------------
template <int MODE>
__global__ __launch_bounds__(512, 2) void k_gemmOut(
    const u16* __restrict__ A, int lda,
    const u16* __restrict__ Bw, int ldb,
    float* __restrict__ Cout, int ldc,
    const float* __restrict__ f2, float* __restrict__ out2)
{
  extern __shared__ __align__(16) char lds[];  // 98304 B

  const int tid  = threadIdx.x;
  const int lane = tid & 63;
  const int wid  = tid >> 6;

  const int mBase = blockIdx.x * 256;
  const int nBase = blockIdx.y * 128;

  // staging: A granule G = i*512 + wid*64 + lane (i=0..3), row = G>>3 (0..255)
  //          B granule G = i*512 + wid*64 + lane (i=0..1), row = G>>3 (0..127)
  // row&7 == lane>>3 in both (i*64, wid*8 are 0 mod 8) -> same swizzle math.
  const int rloc = lane >> 3;                       // 0..7
  const int scol = ((lane & 7) ^ rloc) << 3;        // elems (8 per granule)
  const u16* srcA[4];
  const u16* srcB[2];
#pragma unroll
  for (int i = 0; i < 4; ++i)
    srcA[i] = A + (long long)(mBase + i * 64 + wid * 8 + rloc) * lda + scol;
#pragma unroll
  for (int i = 0; i < 2; ++i)
    srcB[i] = Bw + (long long)(nBase + i * 64 + wid * 8 + rloc) * ldb + scol;
  u16* const dA = (u16*)lds + wid * 512;            // wave A base (64 granules)
  u16* const dB = (u16*)lds + 32768 + wid * 512;    // wave B base

  // ds_read byte offsets: A rows (wid>>1)*64 + fm*16 + (lane&15);
  //                       B rows (wid&1)*64 + fn*16 + (lane&15).
  const int lhi16 = (lane >> 4) * 16;
  const int swz   = (lane & 7) << 4;
  const int rdA   = ((wid >> 1) * 64 + (lane & 15)) * 128 + (lhi16 ^ swz);
  const int rdAx  = rdA ^ 64;                       // kk=1 (+32 elems)
  const int rdB   = 65536 + ((wid & 1) * 64 + (lane & 15)) * 128 + (lhi16 ^ swz);
  const int rdBx  = rdB ^ 64;

  f32x4 acc[4][4];
#pragma unroll
  for (int i = 0; i < 4; ++i)
#pragma unroll
    for (int j = 0; j < 4; ++j) acc[i][j] = (f32x4){0.f, 0.f, 0.f, 0.f};

  bf16x8 af[4][2], bfr[4][2];

#define LDSV(off) (*(const bf16x8*)(lds + (off)))
#define RD_A(CB) do {                                                          \
  _Pragma("unroll") for (int fm = 0; fm < 4; ++fm) {                           \
    af[fm][0] = LDSV((CB)*32768 + fm*2048 + rdA);                              \
    af[fm][1] = LDSV((CB)*32768 + fm*2048 + rdAx); }                           \
} while (0)
#define RD_B(CB) do {                                                          \
  _Pragma("unroll") for (int fn = 0; fn < 4; ++fn) {                           \
    bfr[fn][0] = LDSV((CB)*16384 + fn*2048 + rdB);                             \
    bfr[fn][1] = LDSV((CB)*16384 + fn*2048 + rdBx); }                          \
} while (0)
// stage all of tile KT into buffer CB: A 4 rounds + B 2 rounds (6 loads/thr)
#define STG_ALL(CB, KT) do {                                                   \
  gl_lds16(srcA[0] + (KT)*64, dA + (CB)*16384);                                \
  gl_lds16(srcA[1] + (KT)*64, dA + (CB)*16384 + 4096);                         \
  gl_lds16(srcA[2] + (KT)*64, dA + (CB)*16384 + 8192);                         \
  gl_lds16(srcA[3] + (KT)*64, dA + (CB)*16384 + 12288);                        \
  gl_lds16(srcB[0] + (KT)*64, dB + (CB)*8192);                                 \
  gl_lds16(srcB[1] + (KT)*64, dB + (CB)*8192 + 4096);                          \
} while (0)
#define KTILE3(CB, STG) do {                                                   \
  STG;                                                                         \
  RD_A(CB); RD_B(CB);                                                          \
  LGKM(0); SCHB();                                                             \
  __builtin_amdgcn_s_setprio(1);                                              \
  _Pragma("unroll") for (int fm = 0; fm < 4; ++fm)                             \
  _Pragma("unroll") for (int fn = 0; fn < 4; ++fn)                             \
  _Pragma("unroll") for (int kk = 0; kk < 2; ++kk)                             \
    acc[fm][fn] = __builtin_amdgcn_mfma_f32_16x16x32_bf16(                     \
        af[fm][kk], bfr[fn][kk], acc[fm][fn], 0, 0, 0);                        \
  __builtin_amdgcn_s_setprio(0);                                              \
  VM0(); BAR();                                                                \
} while (0)

  // prologue: tile 0 -> buf0
  STG_ALL(0, 0);
  VM0(); BAR();

  // K = 2048 -> 32 K-tiles; 30 in the steady loop + 2 peeled tail tiles.
  for (int it = 0; it < 15; ++it) {
    const int kt = 2 * it;
    KTILE3(0, STG_ALL(1, kt + 1));
    KTILE3(1, STG_ALL(0, kt + 2));
  }
  KTILE3(0, STG_ALL(1, 31));
  KTILE3(1, NOPS);

  // epilogue: D mapping col = lane&15, row = (lane>>4)*4 + reg  [m89]
  const int rq = (lane >> 4) << 2;
  const int cn = lane & 15;
  const long long mW = mBase + (wid >> 1) * 64;
  const int nW = nBase + (wid & 1) * 64;
#pragma unroll
  for (int fm = 0; fm < 4; ++fm)
#pragma unroll
    for (int fn = 0; fn < 4; ++fn)
#pragma unroll
      for (int r = 0; r < 4; ++r) {
        const long long m = mW + fm * 16 + rq + r;
        const int n = nW + fn * 16 + cn;
        const float v = acc[fm][fn][r];
        if constexpr (MODE == 2) {
          Cout[m * ldc + n] = v;
        } else {  // MODE 3: time-flipped accumulate into final output
          const long long mf = m ^ 2047;
          out2[mf * ldc + n] = v + f2[mf * ldc + n];
        }
      }
#undef LDSV
#undef RD_A
#undef RD_B
#undef STG_ALL
#undef KTILE3
}

// ---------------------------------------------------------------------------
// GEMM: C[m,n] = sum_k A[m,k] * B[n,k]   (both K-major, bf16 in, fp32 acc)
// 128x128 tile, BK=64, 256 threads (4 waves, each 64x64 = 4x4 mfma 16x16x32).
// MODE 1: softplus(acc + f1[n]) -> bf16
// MODE 4: n<64 -> bf16 Cout; n in [64,96) -> split fp32 to f1(B)/f2(C)
// ---------------------------------------------------------------------------
template <int MODE>
__global__ __launch_bounds__(256) void k_gemm(
    const u16* __restrict__ A, int lda, int flipA,
    const u16* __restrict__ Bw, int ldb,
    void* __restrict__ Cout, int ldc, int K,
    float* __restrict__ f1, float* __restrict__ f2,
    float* __restrict__ out2)
{
  __shared__ __align__(16) u16 As[128 * 64];
  __shared__ __align__(16) u16 Bs[128 * 64];

  const int tid  = threadIdx.x;
  const int lane = tid & 63;
  const int wid  = tid >> 6;

  const int mBase = blockIdx.x * 128;
  const int nBase = blockIdx.y * 128;

  f32x4 acc[4][4];
#pragma unroll
  for (int i = 0; i < 4; ++i)
#pragma unroll
    for (int j = 0; j < 4; ++j) acc[i][j] = (f32x4){0.f, 0.f, 0.f, 0.f};

  const int wm = (wid & 1) * 64;
  const int wn = (wid >> 1) * 64;
  const int lrow = lane & 15;
  const int lk   = (lane >> 4) * 8;
  const int sr = tid >> 3;         // staging row within 32-row group [0,32)
  const int sc = (tid & 7) * 8;    // staging col (8 bf16 = 16 B)

  for (int k0 = 0; k0 < K; k0 += 64) {
#pragma unroll
    for (int i = 0; i < 4; ++i) {
      int ra = mBase + i * 32 + sr;
      if (flipA) ra ^= 2047;               // SGPR-uniform time flip
      const int rb = nBase + i * 32 + sr;
      u16* la = &As[(i * 256 + wid * 64) * 8];
      u16* lb = &Bs[(i * 256 + wid * 64) * 8];
      gl_lds16(A  + (long long)ra * lda + (k0 + sc), la);
      gl_lds16(Bw + (long long)rb * ldb + (k0 + sc), lb);
    }
    __syncthreads();
#pragma unroll
    for (int kk = 0; kk < 64; kk += 32) {
      bf16x8 af[4], bfr[4];
#pragma unroll
      for (int f = 0; f < 4; ++f) {
        af[f]  = *(const bf16x8*)&As[(wm + f * 16 + lrow) * 64 + kk + lk];
        bfr[f] = *(const bf16x8*)&Bs[(wn + f * 16 + lrow) * 64 + kk + lk];
      }
#pragma unroll
      for (int fm = 0; fm < 4; ++fm)
#pragma unroll
        for (int fn = 0; fn < 4; ++fn)
          acc[fm][fn] = __builtin_amdgcn_mfma_f32_16x16x32_bf16(af[fm], bfr[fn], acc[fm][fn], 0, 0, 0);
    }
    __syncthreads();
  }

  const int rowq = (lane >> 4) * 4;
  const int coln = lane & 15;
#pragma unroll
  for (int fm = 0; fm < 4; ++fm) {
#pragma unroll
    for (int fn = 0; fn < 4; ++fn) {
#pragma unroll
      for (int r = 0; r < 4; ++r) {
        const long long m = mBase + wm + fm * 16 + rowq + r;
        const long long n = nBase + wn + fn * 16 + coln;
        const float v = acc[fm][fn][r];
        if constexpr (MODE == 0) {
          ((u16*)Cout)[m * ldc + n] = f2b(v);
        } else if constexpr (MODE == 1) {
          ((u16*)Cout)[m * ldc + n] = f2b(fast_softplus(v + f1[(int)n]));
        } else if constexpr (MODE == 2) {
          ((float*)Cout)[m * ldc + n] = v;
        } else if constexpr (MODE == 3) {
          const long long mf = m ^ 2047;  // time flip within batch (L=2048)
          out2[mf * ldc + n] = v + f2[mf * ldc + n];
        } else {  // MODE 4 (x_proj): dt-raw -> proj bf16; B/C -> fp32 split
          if (n < 64)       ((u16*)Cout)[m * ldc + n] = f2b(v);
          else if (n < 80)  f1[m * 16 + (n - 64)] = v;
          else if (n < 96)  f2[m * 16 + (n - 80)] = v;
        }
      }
    }
  }
}

// ---------------------------------------------------------------------------
// fused per-dir prep: [0,4096) castw inw | [4096,5120) pad+cast xw |
// [5120,5248) castw dtw | [5248,5376) A2 | [5376,5408) cwT transpose
// ---------------------------------------------------------------------------
__global__ __launch_bounds__(256) void k_prep(
    const float* __restrict__ inw_d, u16* __restrict__ inwB,
    const float* __restrict__ xpw_d, u16* __restrict__ xw_pad,
    const float* __restrict__ dtw_d, u16* __restrict__ dtwB,
    const float* __restrict__ alog_d, float* __restrict__ A2,
    const float* __restrict__ cw_d, float* __restrict__ cwT)
{
  const int bx = blockIdx.x;
  const int tid = threadIdx.x;
  if (bx < 4096) {
    const int i = bx * 256 + tid;
    const f32x4 v = ((const f32x4*)inw_d)[i];
    u16x4 o = {f2b(v[0]), f2b(v[1]), f2b(v[2]), f2b(v[3])};
    ((u16x4*)inwB)[i] = o;
  } else if (bx < 5120) {
    const int idx = (bx - 4096) * 256 + tid;  // [0, 128*2048)
    const int c = idx & 2047, r = idx >> 11;
    xw_pad[idx] = (r < 96) ? f2b(xpw_d[r * 2048 + c]) : (u16)0;
  } else if (bx < 5248) {
    const int i = (bx - 5120) * 256 + tid;    // 2048*64/4
    const f32x4 v = ((const f32x4*)dtw_d)[i];
    u16x4 o = {f2b(v[0]), f2b(v[1]), f2b(v[2]), f2b(v[3])};
    ((u16x4*)dtwB)[i] = o;
  } else if (bx < 5376) {
    const int idx = (bx - 5248) * 256 + tid;  // [0, 2048*16)
    A2[idx] = -expf(alog_d[idx]) * L2E;  // A * log2(e)
  } else {
    const int idx = (bx - 5376) * 256 + tid;  // [0, 8192)
    const int d = idx & 2047, k = idx >> 11;
    cwT[k * 2048 + d] = cw_d[d * 4 + k];      // [2048][4] -> [4][2048]
  }
}

__global__ __launch_bounds__(256) void k_castw(const float* __restrict__ src,
                                               u16* __restrict__ dst) {
  const int i = blockIdx.x * 256 + threadIdx.x;
  const f32x4 v = ((const f32x4*)src)[i];
  u16x4 o = {f2b(v[0]), f2b(v[1]), f2b(v[2]), f2b(v[3])};
  ((u16x4*)dst)[i] = o;
}

// x fp32 [4][2048][1024] -> bf16 (no flip; dir1 flip happens in GEMM staging)
__global__ __launch_bounds__(256) void k_cast_x(const float* __restrict__ x,
                                                u16* __restrict__ xA) {
  const int idx = blockIdx.x * 256 + threadIdx.x;  // [0, 4*2048*256)
  const f32x4 v = ((const f32x4*)x)[idx];
  u16x4 o = {f2b(v[0]), f2b(v[1]), f2b(v[2]), f2b(v[3])};
  ((u16x4*)xA)[idx] = o;
}

// ---------------------------------------------------------------------------
// depthwise causal conv (k=4) + bias + silu.  xi lives in xz cols [0,2048).
// ---------------------------------------------------------------------------
__global__ __launch_bounds__(256) void k_conv(const u16* __restrict__ xz,
                                              const float* __restrict__ cwT,
                                              const float* __restrict__ cb,
                                              u16* __restrict__ xc) {
  const int idx = blockIdx.x * 256 + threadIdx.x;  // [0, 8192*256)
  const int d8  = idx & 255;
  const int gr  = idx >> 8;
  const int t   = gr & 2047;
  const int d0  = d8 * 8;

  float acc[8];
  {
    const f32x4 b0 = *(const f32x4*)(cb + d0);
    const f32x4 b1 = *(const f32x4*)(cb + d0 + 4);
#pragma unroll
    for (int j = 0; j < 4; ++j) { acc[j] = b0[j]; acc[4 + j] = b1[j]; }
  }

#pragma unroll
  for (int k = 0; k < 4; ++k) {
    const int tt = t - 3 + k;
    if (tt < 0) continue;
    const u32x4 v = *(const u32x4*)(xz + (long long)(gr + k - 3) * 4096 + d0);
    const u16* pv = (const u16*)&v;
    const f32x4 w0 = *(const f32x4*)(cwT + k * 2048 + d0);
    const f32x4 w1 = *(const f32x4*)(cwT + k * 2048 + d0 + 4);
#pragma unroll
    for (int j = 0; j < 4; ++j) {
      acc[j]     = fmaf(w0[j], b2f(pv[j]), acc[j]);
      acc[4 + j] = fmaf(w1[j], b2f(pv[4 + j]), acc[4 + j]);
    }
  }
  u16 o[8];
#pragma unroll
  for (int j = 0; j < 8; ++j) {
    o[j] = f2b(fast_silu(acc[j]));
  }
  *(u32x4*)(xc + (long long)gr * 2048 + d0) = *(const u32x4*)o;
}

// ---------------------------------------------------------------------------
// scan phase A: per-chunk local scan (h from 0), CHUNK=64. Writes ONLY chunk
// summaries hbuf[b][c][s][d] (local end-state) and sumdt[b][c][d].
// grid: 4(b) * 32(chunk) * 8(dchunk) = 1024 blocks
// ---------------------------------------------------------------------------
__global__ __launch_bounds__(256) void k_scanA(
    const u16* __restrict__ dt, const u16* __restrict__ xc,
    const float* __restrict__ Bf, const float* __restrict__ A2,
    float* __restrict__ hbuf, float* __restrict__ sumdt)
{
  const int tid = threadIdx.x;
  const int bx  = blockIdx.x;
  const int d     = (bx & 7) * 256 + tid;
  const int chunk = (bx >> 3) & 31;
  const int b     = bx >> 8;

  float a2[16];
#pragma unroll
  for (int s = 0; s < 16; ++s) a2[s] = A2[d * 16 + s];

  float h[16];
#pragma unroll
  for (int s = 0; s < 16; ++s) h[s] = 0.f;
  float sdt = 0.f;

  const long long rowBase = (long long)b * 2048 + chunk * 64;
  for (int t0 = 0; t0 < 64; ++t0) {
    const long long gr = rowBase + t0;
    const float dtv = b2f(dt[gr * 2048 + d]);
    const float xcv = b2f(xc[gr * 2048 + d]);
    sdt += dtv;
    const float dtx = dtv * xcv;
    float Bv[16];
    *(f32x4*)&Bv[0]  = *(const f32x4*)(Bf + gr * 16);
    *(f32x4*)&Bv[4]  = *(const f32x4*)(Bf + gr * 16 + 4);
    *(f32x4*)&Bv[8]  = *(const f32x4*)(Bf + gr * 16 + 8);
    *(f32x4*)&Bv[12] = *(const f32x4*)(Bf + gr * 16 + 12);
#pragma unroll
    for (int s = 0; s < 16; ++s) {
      const float dA = __builtin_amdgcn_exp2f(a2[s] * dtv);
      h[s] = fmaf(h[s], dA, dtx * Bv[s]);
    }
  }
  const long long cbi = (long long)b * 32 + chunk;
#pragma unroll
  for (int s = 0; s < 16; ++s) hbuf[(cbi * 16 + s) * 2048 + d] = h[s];
  sumdt[cbi * 2048 + d] = sdt;
}

// phase B: chain chunk states IN PLACE: hbuf[c] goes local-end-state ->
// entering-state. s-chains are independent -> split x2 (8 s per block).
// grid: 4(b) * 8(dchunk) * 2(sgroup) = 64 blocks
__global__ __launch_bounds__(256) void k_scanB(
    const float* __restrict__ A2, float* __restrict__ hbuf,
    const float* __restrict__ sumdt)
{
  const int tid = threadIdx.x;
  const int bx  = blockIdx.x;
  const int d   = (bx & 7) * 256 + tid;
  const int sg  = ((bx >> 3) & 1) * 8;
  const int b   = bx >> 4;

  float a2[8];
#pragma unroll
  for (int s = 0; s < 8; ++s) a2[s] = A2[d * 16 + sg + s];
  float h[8];
#pragma unroll
  for (int s = 0; s < 8; ++s) h[s] = 0.f;

  const long long base = (long long)b * 32;
  for (int c = 0; c < 32; ++c) {
    const long long cbi = base + c;
    const float sd = sumdt[cbi * 2048 + d];
#pragma unroll
    for (int s = 0; s < 8; ++s) {
      float* p = &hbuf[(cbi * 16 + sg + s) * 2048 + d];
      const float loc = *p;      // local end-state of chunk c
      *p = h[s];                 // replace with state ENTERING chunk c
      const float P = __builtin_amdgcn_exp2f(a2[s] * sd);
      h[s] = fmaf(h[s], P, loc);
    }
  }
}

// ---------------------------------------------------------------------------
// phase C: true recurrence from entering state + gate, y written once.
// y = h.C with h = h*dA + dtx*B stepped from hbuf state; then
// y_fin = (y + xc*Dp) * silu(z). grid 1024 (same decomposition as A).
// ---------------------------------------------------------------------------
__global__ __launch_bounds__(256) void k_scanC(
    const u16* __restrict__ dt, const u16* __restrict__ xc,
    const float* __restrict__ Bf, const float* __restrict__ Cf,
    const float* __restrict__ A2, const float* __restrict__ hbuf,
    const float* __restrict__ Dp, u16* __restrict__ yz)
{
  const int tid = threadIdx.x;
  const int bx  = blockIdx.x;
  const int d     = (bx & 7) * 256 + tid;
  const int chunk = (bx >> 3) & 31;
  const int b     = bx >> 8;
  const float dp  = Dp[d];

  float a2[16];
#pragma unroll
  for (int s = 0; s < 16; ++s) a2[s] = A2[d * 16 + s];

  const long long cbi = (long long)b * 32 + chunk;
  float h[16];
#pragma unroll
  for (int s = 0; s < 16; ++s) h[s] = hbuf[(cbi * 16 + s) * 2048 + d];

  const long long rowBase = (long long)b * 2048 + chunk * 64;
  for (int t0 = 0; t0 < 64; ++t0) {
    const long long gr = rowBase + t0;
    const float dtv = b2f(dt[gr * 2048 + d]);
    const float xcv = b2f(xc[gr * 2048 + d]);
    const float dtx = dtv * xcv;
    float Bv[16], Cv[16];
    *(f32x4*)&Bv[0]  = *(const f32x4*)(Bf + gr * 16);
    *(f32x4*)&Bv[4]  = *(const f32x4*)(Bf + gr * 16 + 4);
    *(f32x4*)&Bv[8]  = *(const f32x4*)(Bf + gr * 16 + 8);
    *(f32x4*)&Bv[12] = *(const f32x4*)(Bf + gr * 16 + 12);
    *(f32x4*)&Cv[0]  = *(const f32x4*)(Cf + gr * 16);
    *(f32x4*)&Cv[4]  = *(const f32x4*)(Cf + gr * 16 + 4);
    *(f32x4*)&Cv[8]  = *(const f32x4*)(Cf + gr * 16 + 8);
    *(f32x4*)&Cv[12] = *(const f32x4*)(Cf + gr * 16 + 12);
    float y = 0.f;
#pragma unroll
    for (int s = 0; s < 16; ++s) {
      const float dA = __builtin_amdgcn_exp2f(a2[s] * dtv);
      h[s] = fmaf(h[s], dA, dtx * Bv[s]);
      y = fmaf(h[s], Cv[s], y);
    }
    const float z = b2f(yz[gr * 4096 + 2048 + d]);
    const float yv = (y + xcv * dp) * fast_silu(z);
    yz[gr * 4096 + d] = f2b(yv);
  }
}

// ---------------------------------------------------------------------------
extern "C" void kernel_launch(void* const* d_in, const int* in_sizes, int n_in,
                              void* d_out, int out_size, void* d_ws, size_t ws_size,
                              hipStream_t stream) {
  const float* x    = (const float*)d_in[0];
  const float* inw  = (const float*)d_in[1];
  const float* cw   = (const float*)d_in[2];
  const float* cb   = (const float*)d_in[3];
  const float* xpw  = (const float*)d_in[4];
  const float* dtw  = (const float*)d_in[5];
  const float* dtb  = (const float*)d_in[6];
  const float* alog = (const float*)d_in[7];
  const float* Dp   = (const float*)d_in[8];
  const float* ow   = (const float*)d_in[9];
  float* out = (float*)d_out;

  // workspace layout (bytes) — per-direction buffers reused across dir 0/1.
  char* ws = (char*)d_ws;
  float* outacc = (float*)(ws + 0);          //  33,554,432  [8192][1024] fp32
  u16*   xz_d   = (u16*)(ws + 33554432);     //  67,108,864  [8192][4096] xi|z -> y|z
  u16*   xc_d   = (u16*)(ws + 100663296);    //  33,554,432  [8192][2048]
  u16*   inwB   = (u16*)(ws + 100663296);    //   8,388,608  (xc dead during in_proj)
  u16*   dt_d   = (u16*)(ws + 134217728);    //  33,554,432  [8192][2048]
  u16*   owB    = (u16*)(ws + 134217728);    //   4,194,304  (dt dead after scanC)
  u16*   xA     = (u16*)(ws + 167772160);    //  16,777,216  [8192][1024] persistent
  u16*   proj_d = (u16*)(ws + 184549376);    //   1,048,576  [8192][64] (stride 64)
  u16*   xw_pad = (u16*)(ws + 185597952);    //     524,288  [128][2048]
  float* A2     = (float*)(ws + 186122240);  //     131,072  [2048][16]
  float* Bf     = (float*)(ws + 186253312);  //     524,288  [8192][16]
  float* Cf     = (float*)(ws + 186777600);  //     524,288
  float* hbuf   = (float*)(ws + 187301888);  //  16,777,216  [4][32][16][2048] in-place
  float* sumdt  = (float*)(ws + 204079104);  //   1,048,576  [4][32][2048]
  u16*   dtwB   = (u16*)(ws + 205127680);    //     262,144  [2048][64]
  float* cwT    = (float*)(ws + 205389824);  //      32,768  [4][2048]
  const size_t NEED = 205422592;  // <= 205,651,968 proven available (R2 ran)

  (void)in_sizes; (void)n_in; (void)out_size;
  if (ws_size < NEED) {  // deterministic guard: leaves d_out zeroed -> clean fail
    fprintf(stderr, "[BiMamba] ws_size=%zu < needed %zu — aborting launch\n", ws_size, NEED);
    return;
  }

  // allow >64 KiB dynamic LDS (host-side, capture-safe)
  static bool attr_set = false;
  if (!attr_set) {
    (void)hipFuncSetAttribute((const void*)k_gemm256,
                              hipFuncAttributeMaxDynamicSharedMemorySize, 131072);
    (void)hipFuncSetAttribute((const void*)k_gemmOut<2>,
                              hipFuncAttributeMaxDynamicSharedMemorySize, 98304);
    (void)hipFuncSetAttribute((const void*)k_gemmOut<3>,
                              hipFuncAttributeMaxDynamicSharedMemorySize, 98304);
    attr_set = true;
  }

  k_cast_x<<<8192, 256, 0, stream>>>(x, xA);  // once; dir1 flips in staging

  for (int dir = 0; dir < 2; ++dir) {
    const float* inw_d = inw + (long long)dir * 4096 * 1024;
    const float* cw_d  = cw  + dir * 2048 * 4;
    const float* cb_d  = cb  + dir * 2048;
    const float* xpw_d = xpw + dir * 96 * 2048;
    const float* dtw_d = dtw + dir * 2048 * 64;
    const float* dtb_d = dtb + dir * 2048;
    const float* al_d  = alog + dir * 2048 * 16;
    const float* Dp_d  = Dp  + dir * 2048;
    const float* ow_d  = ow  + (long long)dir * 1024 * 2048;

    k_prep<<<5408, 256, 0, stream>>>(inw_d, inwB, xpw_d, xw_pad,
                                     dtw_d, dtwB, al_d, A2, cw_d, cwT);

    // in_proj: xz = xA[8192,1024] x inwB[4096,1024]^T  (dir1: A rows ^2047)
    // 256^2 ping-pong template, 512 thr, 128 KiB LDS
    k_gemm256<<<dim3(32, 16), 512, 131072, stream>>>(
        xA, 1024, dir, inwB, 1024, xz_d, 4096, 1024);

    k_conv<<<8192, 256, 0, stream>>>(xz_d, cwT, cb_d, xc_d);

    // x_proj: proj(dt-raw, stride 64) + Bf/Cf fp32 split, fused epilogue
    k_gemm<4><<<dim3(64, 1), 256, 0, stream>>>(
        xc_d, 2048, 0, xw_pad, 2048, proj_d, 64, 2048, Bf, Cf, nullptr);

    // dt_proj: dt = softplus(proj[8192,64] x dtwB[2048,64]^T + dtb)
    k_gemm<1><<<dim3(64, 16), 256, 0, stream>>>(
        proj_d, 64, 0, dtwB, 64, dt_d, 2048, 64,
        const_cast<float*>(dtb_d), nullptr, nullptr);

    k_scanA<<<1024, 256, 0, stream>>>(dt_d, xc_d, Bf, A2, hbuf, sumdt);
    k_scanB<<<64, 256, 0, stream>>>(A2, hbuf, sumdt);
    k_scanC<<<1024, 256, 0, stream>>>(dt_d, xc_d, Bf, Cf, A2, hbuf, Dp_d, xz_d);

    // out_proj weights -> bf16 (dt region dead after scanC)
    k_castw<<<2048, 256, 0, stream>>>(ow_d, owB);

    // out_proj: 256x128 ping-pong, grid 256 blocks (1/CU), 96 KiB LDS
    if (dir == 0) {
      k_gemmOut<2><<<dim3(32, 8), 512, 98304, stream>>>(
          xz_d, 4096, owB, 2048, outacc, 1024, nullptr, nullptr);
    } else {
      k_gemmOut<3><<<dim3(32, 8), 512, 98304, stream>>>(
          xz_d, 4096, owB, 2048, nullptr, 1024, outacc, out);
    }
  }
}